// Round 6
// baseline (1411.101 us; speedup 1.0000x reference)
//
#include <hip/hip_runtime.h>
#include <math.h>

// Problem constants (match reference)
#define NN 20000
#define T_IN 8
#define FEAT 16
#define HID 128
#define H3 384
#define FUSER_IN 49
#define FUSER_H 96
#define GATE_H 48
#define ALPHA 0.5f

typedef unsigned short u16;
typedef __attribute__((ext_vector_type(8))) short bf16x8_t;
typedef __attribute__((ext_vector_type(4))) float f32x4_t;

__device__ __forceinline__ float sigmoidf_(float v) { return 1.0f / (1.0f + expf(-v)); }

// bf16 round-to-nearest-even (finite values only)
__device__ __forceinline__ u16 f2b(float v) {
    unsigned u = __float_as_uint(v);
    unsigned r = (u + 0x7fffu + ((u >> 16) & 1u)) >> 16;
    return (u16)r;
}
__device__ __forceinline__ float b2f(u16 u) { return __uint_as_float(((unsigned)u) << 16); }

// ---------------- preprocessing ----------------

__global__ void init_kernel(int* first_eid, int* deg_cnt, int n) {
    int i = blockIdx.x * 256 + threadIdx.x;
    if (i < n) { first_eid[i] = 0x7fffffff; deg_cnt[i] = 0; }
}

__global__ void edge_pass1(const int* __restrict__ src, const int* __restrict__ dst,
                           int* first_eid, int* deg_cnt, int e) {
    int i = blockIdx.x * 256 + threadIdx.x;
    if (i < e) {
        atomicMin(&first_eid[src[i]], i);
        atomicAdd(&deg_cnt[dst[i]], 1);
    }
}

// 3-phase parallel prefix sum over cnt[n] (n <= 256*256)
__global__ void scan1(const int* __restrict__ cnt, int* tmp, int* bsum, int n) {
    __shared__ int buf[256];
    int tid = threadIdx.x;
    int i = blockIdx.x * 256 + tid;
    int v = (i < n) ? cnt[i] : 0;
    buf[tid] = v;
    __syncthreads();
    #pragma unroll
    for (int off = 1; off < 256; off <<= 1) {
        int t = (tid >= off) ? buf[tid - off] : 0;
        __syncthreads();
        buf[tid] += t;
        __syncthreads();
    }
    if (i < n) tmp[i] = buf[tid];
    if (tid == 255) bsum[blockIdx.x] = buf[255];
}

__global__ void scan2(int* bsum, int nb) {
    __shared__ int buf[256];
    int tid = threadIdx.x;
    int v = (tid < nb) ? bsum[tid] : 0;
    buf[tid] = v;
    __syncthreads();
    #pragma unroll
    for (int off = 1; off < 256; off <<= 1) {
        int t = (tid >= off) ? buf[tid - off] : 0;
        __syncthreads();
        buf[tid] += t;
        __syncthreads();
    }
    if (tid < nb) bsum[tid] = buf[tid];   // inclusive block sums
}

__global__ void scan3(const int* __restrict__ cnt, const int* __restrict__ tmp,
                      const int* __restrict__ bsum,
                      int* row_ptr, int* fill_ptr, float* dis, float* norm_self, int n) {
    int i = blockIdx.x * 256 + threadIdx.x;
    if (i >= n) return;
    int pre = (blockIdx.x > 0) ? bsum[blockIdx.x - 1] : 0;
    int incl = tmp[i] + pre;
    int v = cnt[i];
    row_ptr[i + 1] = incl;
    fill_ptr[i] = incl - v;
    float deg = (float)v + 1.0f;
    dis[i] = 1.0f / sqrtf(deg);
    norm_self[i] = 1.0f / deg;
    if (i == 0) row_ptr[0] = 0;
}

__global__ void firsts_kernel(const int* __restrict__ first_eid, const int* __restrict__ dst,
                              const float* __restrict__ edge_attr,
                              int* first_out, float* first_dx, int n, int e) {
    int i = blockIdx.x * 256 + threadIdx.x;
    if (i >= n) return;
    int fe = first_eid[i];
    if (fe < e) {
        first_out[i] = dst[fe];
        first_dx[i] = fmaxf(edge_attr[fe], 1e-6f);
    } else {
        first_out[i] = -1;
        first_dx[i] = -1.0f;
    }
}

__global__ void edge_pass2(const int* __restrict__ src, const int* __restrict__ dst,
                           int* fill_ptr, const float* __restrict__ dis,
                           int* csr_src, float* csr_w, int e) {
    int i = blockIdx.x * 256 + threadIdx.x;
    if (i < e) {
        int d = dst[i], s = src[i];
        int pos = atomicAdd(&fill_ptr[d], 1);
        csr_src[pos] = s;
        csr_w[pos] = dis[s] * dis[d];
    }
}

__global__ void ghost_kernel(const int* __restrict__ mask, const int* __restrict__ first_out,
                             const float* __restrict__ first_dx,
                             int* d1_of, int* d2_of, float* dxb_of, int n) {
    int i = blockIdx.x * 256 + threadIdx.x;
    if (i >= n || mask[i] != 0) return;
    int b = first_out[i];
    float dxb = fmaxf(first_dx[i], 1e-6f);
    int d1, d2;
    if (b < 0) { d1 = i; d2 = i; }
    else {
        int n1 = first_out[b]; d1 = (n1 < 0) ? b : n1;
        int n2 = first_out[d1]; d2 = (n2 < 0) ? d1 : n2;
    }
    d1_of[i] = d1; d2_of[i] = d2; dxb_of[i] = dxb;
}

// zero two regions in one dispatch (grid-stride)
__global__ void zero2_kernel(float* a, int na, unsigned* b, int nb) {
    int stride = gridDim.x * 256;
    for (int i = blockIdx.x * 256 + threadIdx.x; i < na; i += stride) a[i] = 0.0f;
    for (int i = blockIdx.x * 256 + threadIdx.x; i < nb; i += stride) b[i] = 0u;
}

// W[k][nn] (K=128) -> BT_hi/BT_lo[nn][k] bf16 split, LDS-tiled transpose (coalesced both sides)
__global__ __launch_bounds__(256)
void wsplit_kernel(const float* __restrict__ W, u16* BT_hi, u16* BT_lo, int Ncols) {
    __shared__ float tile[32][33];
    int nb = blockIdx.x * 32;           // column-of-W (=row-of-BT) base
    int kb = blockIdx.y * 32;           // k base
    int tx = threadIdx.x & 31, ty = threadIdx.x >> 5;   // 32 x 8
    #pragma unroll
    for (int r = 0; r < 32; r += 8)
        tile[ty + r][tx] = W[(size_t)(kb + ty + r) * Ncols + nb + tx];
    __syncthreads();
    #pragma unroll
    for (int r = 0; r < 32; r += 8) {
        float v = tile[tx][ty + r];     // = W[kb+tx][nb+ty+r]
        u16 h = f2b(v);
        size_t off = (size_t)(nb + ty + r) * 128 + kb + tx;
        BT_hi[off] = h;
        BT_lo[off] = f2b(v - b2f(h));
    }
}

// ---------------- per-step kernels ----------------

// One block (128 threads) per node: ghost fusion (if ghost) + g = relu(x_fused @ W_lin + b_lin)
__global__ __launch_bounds__(128)
void fuse_lin_kernel(const float* __restrict__ x, const int* __restrict__ mask,
                     const int* __restrict__ d1_of, const int* __restrict__ d2_of,
                     const float* __restrict__ dxb_of,
                     const float* __restrict__ Wf1, const float* __restrict__ bf1,
                     const float* __restrict__ Wf2, const float* __restrict__ bf2,
                     const float* __restrict__ Wg1, const float* __restrict__ bg1,
                     const float* __restrict__ Wg2, const float* __restrict__ bg2,
                     const float* __restrict__ W_lin, const float* __restrict__ b_lin,
                     u16* __restrict__ g_hi, u16* __restrict__ g_lo, int t) {
    int i = blockIdx.x;
    int j = threadIdx.x;
    __shared__ float feats[FUSER_IN];
    __shared__ float xf[FEAT];
    __shared__ float z1[FUSER_H];
    __shared__ float zg[GATE_H];
    __shared__ float s_gate;

    const float* xrow = &x[(i * T_IN + t) * FEAT];
    if (j < FEAT) { float v = xrow[j]; feats[j] = v; xf[j] = v; }

    bool ghost = (mask[i] == 0);
    if (ghost) {
        if (j < FEAT) {
            int d1 = d1_of[i], d2 = d2_of[i];
            feats[FEAT + j]     = x[(d1 * T_IN + t) * FEAT + j];
            feats[2 * FEAT + j] = x[(d2 * T_IN + t) * FEAT + j];
        }
        if (j == 0) feats[3 * FEAT] = dxb_of[i];
        __syncthreads();
        if (j < FUSER_H) {
            float acc = bf1[j];
            for (int k = 0; k < FUSER_IN; ++k) acc = fmaf(feats[k], Wf1[k * FUSER_H + j], acc);
            z1[j] = fmaxf(acc, 0.0f);
        }
        if (j < GATE_H) {
            float acc = bg1[j];
            for (int k = 0; k < FUSER_IN; ++k) acc = fmaf(feats[k], Wg1[k * GATE_H + j], acc);
            zg[j] = fmaxf(acc, 0.0f);
        }
        __syncthreads();
        if (j == 0) {
            float s = bg2[0];
            for (int k = 0; k < GATE_H; ++k) s = fmaf(zg[k], Wg2[k], s);
            s_gate = sigmoidf_(s);
        }
        __syncthreads();
        if (j < FEAT) {
            float acc = bf2[j];
            for (int k = 0; k < FUSER_H; ++k) acc = fmaf(z1[k], Wf2[k * FEAT + j], acc);
            xf[j] = feats[j] + ALPHA * acc * s_gate;
        }
    }
    __syncthreads();
    float acc = b_lin[j];
    #pragma unroll
    for (int k = 0; k < FEAT; ++k) acc = fmaf(xf[k], W_lin[k * HID + j], acc);
    float v = fmaxf(acc, 0.0f);
    u16 hv = f2b(v);
    g_hi[(size_t)i * HID + j] = hv;
    g_lo[(size_t)i * HID + j] = f2b(v - b2f(hv));
}

// C[M x Ncols] (fp32) = A[M x 128] @ B[128 x Ncols] via bf16x3 split MFMA.
// BM=64, BN=128, 4 waves (2x2). K=128 fully in LDS (XOR-swizzled).
// EPI==1 additionally writes bf16(C) into Cb (for the gather in gcn_agg).
template<int BM, int EPI>
__global__ __launch_bounds__(256)
void gemm_mfma(const u16* __restrict__ Ahi, const u16* __restrict__ Alo,
               const u16* __restrict__ BThi, const u16* __restrict__ BTlo,
               float* __restrict__ C, u16* __restrict__ Cb,
               int M, int Ncols) {
    __shared__ u16 ldsA[2][BM * 128];   // [hi/lo][row*128+k], XOR-swizzled
    const int tid  = threadIdx.x;
    const int row0 = blockIdx.x * BM;
    const int col0 = blockIdx.y * 128;
    constexpr int MF = BM / 32;          // m-fragments per wave (wave tile BM/2 x 64)

    // stage A hi+lo: BM*16 16B-units per component
    #pragma unroll
    for (int it = 0; it < BM / 16; ++it) {
        int unit = tid + it * 256;
        int r = unit >> 4, s = unit & 15;
        int gr = row0 + r;
        uint4 vh = make_uint4(0, 0, 0, 0), vl = vh;
        if (gr < M) {
            vh = *reinterpret_cast<const uint4*>(&Ahi[(size_t)gr * 128 + s * 8]);
            vl = *reinterpret_cast<const uint4*>(&Alo[(size_t)gr * 128 + s * 8]);
        }
        int byte = (r * 256 + s * 16) ^ ((r & 7) << 4);
        *reinterpret_cast<uint4*>((char*)(&ldsA[0][0]) + byte) = vh;
        *reinterpret_cast<uint4*>((char*)(&ldsA[1][0]) + byte) = vl;
    }
    __syncthreads();

    const int wid  = tid >> 6;
    const int lane = tid & 63;
    const int wr = (wid >> 1) * (BM / 2);
    const int wc = (wid & 1) * 64;
    const int l15 = lane & 15;
    const int lkh = lane >> 4;          // k-chunk 0..3

    f32x4_t acc[MF][4] = {};

    #pragma unroll
    for (int kb = 0; kb < 4; ++kb) {
        bf16x8_t ah[MF], al[MF], bh[4], bl[4];
        #pragma unroll
        for (int m = 0; m < MF; ++m) {
            int row = wr + m * 16 + l15;
            int byte = (row * 256 + kb * 64 + lkh * 16) ^ ((row & 7) << 4);
            ah[m] = *reinterpret_cast<const bf16x8_t*>((const char*)(&ldsA[0][0]) + byte);
            al[m] = *reinterpret_cast<const bf16x8_t*>((const char*)(&ldsA[1][0]) + byte);
        }
        #pragma unroll
        for (int nf = 0; nf < 4; ++nf) {
            int col = col0 + wc + nf * 16 + l15;
            size_t off = (size_t)col * 128 + kb * 32 + lkh * 8;
            bh[nf] = *reinterpret_cast<const bf16x8_t*>(&BThi[off]);
            bl[nf] = *reinterpret_cast<const bf16x8_t*>(&BTlo[off]);
        }
        #pragma unroll
        for (int m = 0; m < MF; ++m)
            #pragma unroll
            for (int nf = 0; nf < 4; ++nf) {
                acc[m][nf] = __builtin_amdgcn_mfma_f32_16x16x32_bf16(ah[m], bh[nf], acc[m][nf], 0, 0, 0);
                acc[m][nf] = __builtin_amdgcn_mfma_f32_16x16x32_bf16(ah[m], bl[nf], acc[m][nf], 0, 0, 0);
                acc[m][nf] = __builtin_amdgcn_mfma_f32_16x16x32_bf16(al[m], bh[nf], acc[m][nf], 0, 0, 0);
            }
    }

    #pragma unroll
    for (int m = 0; m < MF; ++m) {
        int rbase = row0 + wr + m * 16 + lkh * 4;
        #pragma unroll
        for (int nf = 0; nf < 4; ++nf) {
            int col = col0 + wc + nf * 16 + l15;
            #pragma unroll
            for (int r2 = 0; r2 < 4; ++r2) {
                int row = rbase + r2;
                if (row < M) {
                    float v = acc[m][nf][r2];
                    C[(size_t)row * Ncols + col] = v;
                    if constexpr (EPI == 1) Cb[(size_t)row * Ncols + col] = f2b(v);
                }
            }
        }
    }
}

// Fused GRU: per 16-row block, gi = g@W_ih, gh = h@W_hh (K=128 in LDS, bf16x3 MFMA),
// gates in epilogue, writes h (fp32) + h_hi/h_lo (bf16 split). No gi/gh round-trip.
// 4 waves; wave w owns HID-cols [w*32, w*32+32) across all 3 gates of BOTH GEMMs
// so gate math is thread-local (C-frag layout identical across the 12 accumulators).
__global__ __launch_bounds__(256)
void gru_fused(const u16* __restrict__ g_hi, const u16* __restrict__ g_lo,
               const u16* __restrict__ WihT_hi, const u16* __restrict__ WihT_lo,
               const u16* __restrict__ WhhT_hi, const u16* __restrict__ WhhT_lo,
               const float* __restrict__ b_ih, const float* __restrict__ b_hh,
               float* __restrict__ h, u16* __restrict__ h_hi, u16* __restrict__ h_lo,
               int n) {
    __shared__ u16 lds[4 * 16 * 128];   // [ghi|glo|hhi|hlo] 16 rows x 128, XOR-swizzled
    const int tid  = threadIdx.x;
    const int row0 = blockIdx.x * 16;

    {   // stage: each thread one 16B unit per component
        int r = tid >> 4, s = tid & 15;
        int gr = row0 + r;
        uint4 vgh = make_uint4(0,0,0,0), vgl = vgh, vhh = vgh, vhl = vgh;
        if (gr < n) {
            size_t goff = (size_t)gr * 128 + s * 8;
            vgh = *reinterpret_cast<const uint4*>(&g_hi[goff]);
            vgl = *reinterpret_cast<const uint4*>(&g_lo[goff]);
            vhh = *reinterpret_cast<const uint4*>(&h_hi[goff]);
            vhl = *reinterpret_cast<const uint4*>(&h_lo[goff]);
        }
        int byte = (r * 256 + s * 16) ^ ((r & 7) << 4);
        char* base = (char*)lds;
        *reinterpret_cast<uint4*>(base + byte)         = vgh;
        *reinterpret_cast<uint4*>(base + 4096 + byte)  = vgl;
        *reinterpret_cast<uint4*>(base + 8192 + byte)  = vhh;
        *reinterpret_cast<uint4*>(base + 12288 + byte) = vhl;
    }
    __syncthreads();

    const int wid  = tid >> 6;
    const int lane = tid & 63;
    const int l15  = lane & 15;
    const int lkh  = lane >> 4;           // 0..3
    const int colbase = wid * 32;         // HID columns owned by this wave

    f32x4_t agi[3][2] = {};               // [gate][cf]
    f32x4_t agh[3][2] = {};

    #pragma unroll
    for (int kb = 0; kb < 4; ++kb) {
        int byte = (l15 * 256 + kb * 64 + lkh * 16) ^ ((l15 & 7) << 4);
        const char* base = (const char*)lds;
        bf16x8_t Agh = *reinterpret_cast<const bf16x8_t*>(base + byte);
        bf16x8_t Agl = *reinterpret_cast<const bf16x8_t*>(base + 4096 + byte);
        bf16x8_t Ahh = *reinterpret_cast<const bf16x8_t*>(base + 8192 + byte);
        bf16x8_t Ahl = *reinterpret_cast<const bf16x8_t*>(base + 12288 + byte);
        #pragma unroll
        for (int gt = 0; gt < 3; ++gt) {
            #pragma unroll
            for (int cf = 0; cf < 2; ++cf) {
                int col = gt * HID + colbase + cf * 16 + l15;    // 0..383
                size_t off = (size_t)col * 128 + kb * 32 + lkh * 8;
                bf16x8_t bih = *reinterpret_cast<const bf16x8_t*>(&WihT_hi[off]);
                bf16x8_t bil = *reinterpret_cast<const bf16x8_t*>(&WihT_lo[off]);
                bf16x8_t bhh = *reinterpret_cast<const bf16x8_t*>(&WhhT_hi[off]);
                bf16x8_t bhl = *reinterpret_cast<const bf16x8_t*>(&WhhT_lo[off]);
                agi[gt][cf] = __builtin_amdgcn_mfma_f32_16x16x32_bf16(Agh, bih, agi[gt][cf], 0, 0, 0);
                agi[gt][cf] = __builtin_amdgcn_mfma_f32_16x16x32_bf16(Agh, bil, agi[gt][cf], 0, 0, 0);
                agi[gt][cf] = __builtin_amdgcn_mfma_f32_16x16x32_bf16(Agl, bih, agi[gt][cf], 0, 0, 0);
                agh[gt][cf] = __builtin_amdgcn_mfma_f32_16x16x32_bf16(Ahh, bhh, agh[gt][cf], 0, 0, 0);
                agh[gt][cf] = __builtin_amdgcn_mfma_f32_16x16x32_bf16(Ahh, bhl, agh[gt][cf], 0, 0, 0);
                agh[gt][cf] = __builtin_amdgcn_mfma_f32_16x16x32_bf16(Ahl, bhh, agh[gt][cf], 0, 0, 0);
            }
        }
    }

    // epilogue: C layout col=lane&15, row=(lane>>4)*4+reg
    #pragma unroll
    for (int cf = 0; cf < 2; ++cf) {
        int col = colbase + cf * 16 + l15;
        float bir = b_ih[col], biz = b_ih[HID + col], bin_ = b_ih[2 * HID + col];
        float bhr = b_hh[col], bhz = b_hh[HID + col], bhn = b_hh[2 * HID + col];
        #pragma unroll
        for (int r2 = 0; r2 < 4; ++r2) {
            int grow = row0 + lkh * 4 + r2;
            if (grow >= n) continue;
            float gir = agi[0][cf][r2] + bir;
            float giz = agi[1][cf][r2] + biz;
            float gin = agi[2][cf][r2] + bin_;
            float ghr = agh[0][cf][r2] + bhr;
            float ghz = agh[1][cf][r2] + bhz;
            float ghn = agh[2][cf][r2] + bhn;
            float rr = sigmoidf_(gir + ghr);
            float zz = sigmoidf_(giz + ghz);
            float nn2 = tanhf(gin + rr * ghn);
            size_t off = (size_t)grow * HID + col;
            float hold = h[off];
            float hnew = (1.0f - zz) * nn2 + zz * hold;
            h[off] = hnew;
            u16 hv = f2b(hnew);
            h_hi[off] = hv;
            h_lo[off] = f2b(hnew - b2f(hv));
        }
    }
}

// out[node][:] = relu(sum_in bf16(hw[src])*w + hw[node]*norm_self + bias) -> bf16 hi/lo split
// 32 threads/node, gathers ushort4 (8B/lane, 256B/edge); self term fp32.
__global__ __launch_bounds__(256)
void gcn_agg(const float* __restrict__ hw, const u16* __restrict__ hwb,
             const int* __restrict__ row_ptr,
             const int* __restrict__ csr_src, const float* __restrict__ csr_w,
             const float* __restrict__ norm_self, const float* __restrict__ bias,
             u16* __restrict__ g_hi, u16* __restrict__ g_lo, int n) {
    int node = blockIdx.x * 8 + (threadIdx.x >> 5);
    int lane = threadIdx.x & 31;
    if (node >= n) return;
    const float4* hw4 = reinterpret_cast<const float4*>(hw);
    float4 self = hw4[(size_t)node * 32 + lane];
    float ns = norm_self[node];
    float4 a0, a1, a2, a3;
    a0.x = self.x * ns; a0.y = self.y * ns; a0.z = self.z * ns; a0.w = self.w * ns;
    a1 = make_float4(0.f, 0.f, 0.f, 0.f); a2 = a1; a3 = a1;
    int p  = row_ptr[node];
    int p1 = row_ptr[node + 1];
    for (; p + 4 <= p1; p += 4) {
        int s0 = csr_src[p], s1 = csr_src[p + 1], s2 = csr_src[p + 2], s3 = csr_src[p + 3];
        float w0 = csr_w[p], w1 = csr_w[p + 1], w2 = csr_w[p + 2], w3 = csr_w[p + 3];
        ushort4 v0 = *reinterpret_cast<const ushort4*>(&hwb[(size_t)s0 * HID + lane * 4]);
        ushort4 v1 = *reinterpret_cast<const ushort4*>(&hwb[(size_t)s1 * HID + lane * 4]);
        ushort4 v2 = *reinterpret_cast<const ushort4*>(&hwb[(size_t)s2 * HID + lane * 4]);
        ushort4 v3 = *reinterpret_cast<const ushort4*>(&hwb[(size_t)s3 * HID + lane * 4]);
        a0.x = fmaf(b2f(v0.x), w0, a0.x); a0.y = fmaf(b2f(v0.y), w0, a0.y);
        a0.z = fmaf(b2f(v0.z), w0, a0.z); a0.w = fmaf(b2f(v0.w), w0, a0.w);
        a1.x = fmaf(b2f(v1.x), w1, a1.x); a1.y = fmaf(b2f(v1.y), w1, a1.y);
        a1.z = fmaf(b2f(v1.z), w1, a1.z); a1.w = fmaf(b2f(v1.w), w1, a1.w);
        a2.x = fmaf(b2f(v2.x), w2, a2.x); a2.y = fmaf(b2f(v2.y), w2, a2.y);
        a2.z = fmaf(b2f(v2.z), w2, a2.z); a2.w = fmaf(b2f(v2.w), w2, a2.w);
        a3.x = fmaf(b2f(v3.x), w3, a3.x); a3.y = fmaf(b2f(v3.y), w3, a3.y);
        a3.z = fmaf(b2f(v3.z), w3, a3.z); a3.w = fmaf(b2f(v3.w), w3, a3.w);
    }
    for (; p < p1; ++p) {
        int s = csr_src[p];
        float w = csr_w[p];
        ushort4 v = *reinterpret_cast<const ushort4*>(&hwb[(size_t)s * HID + lane * 4]);
        a0.x = fmaf(b2f(v.x), w, a0.x); a0.y = fmaf(b2f(v.y), w, a0.y);
        a0.z = fmaf(b2f(v.z), w, a0.z); a0.w = fmaf(b2f(v.w), w, a0.w);
    }
    float4 b4 = reinterpret_cast<const float4*>(bias)[lane];
    float ox = fmaxf(a0.x + a1.x + a2.x + a3.x + b4.x, 0.0f);
    float oy = fmaxf(a0.y + a1.y + a2.y + a3.y + b4.y, 0.0f);
    float oz = fmaxf(a0.z + a1.z + a2.z + a3.z + b4.z, 0.0f);
    float ow = fmaxf(a0.w + a1.w + a2.w + a3.w + b4.w, 0.0f);
    ushort4 hv, lv;
    hv.x = f2b(ox); lv.x = f2b(ox - b2f(hv.x));
    hv.y = f2b(oy); lv.y = f2b(oy - b2f(hv.y));
    hv.z = f2b(oz); lv.z = f2b(oz - b2f(hv.z));
    hv.w = f2b(ow); lv.w = f2b(ow - b2f(hv.w));
    *reinterpret_cast<ushort4*>(&g_hi[(size_t)node * HID + lane * 4]) = hv;
    *reinterpret_cast<ushort4*>(&g_lo[(size_t)node * HID + lane * 4]) = lv;
}

// ---------------- launcher ----------------

extern "C" void kernel_launch(void* const* d_in, const int* in_sizes, int n_in,
                              void* d_out, int out_size, void* d_ws, size_t ws_size,
                              hipStream_t stream) {
    const float* x        = (const float*)d_in[0];
    const float* edge_attr= (const float*)d_in[1];
    const float* W_lin    = (const float*)d_in[2];
    const float* b_lin    = (const float*)d_in[3];
    const float* Wc1      = (const float*)d_in[4];
    const float* bc1      = (const float*)d_in[5];
    const float* Wc2      = (const float*)d_in[6];
    const float* bc2      = (const float*)d_in[7];
    const float* W_ih     = (const float*)d_in[8];
    const float* b_ih     = (const float*)d_in[9];
    const float* W_hh     = (const float*)d_in[10];
    const float* b_hh     = (const float*)d_in[11];
    const float* Wf1      = (const float*)d_in[12];
    const float* bf1      = (const float*)d_in[13];
    const float* Wf2      = (const float*)d_in[14];
    const float* bf2      = (const float*)d_in[15];
    const float* Wg1      = (const float*)d_in[16];
    const float* bg1      = (const float*)d_in[17];
    const float* Wg2      = (const float*)d_in[18];
    const float* bg2      = (const float*)d_in[19];
    const int*   edge_index = (const int*)d_in[20];
    const int*   mask     = (const int*)d_in[21];

    const int n = in_sizes[21];       // 20000
    const int e = in_sizes[1];        // 320000
    const int* src = edge_index;
    const int* dst = edge_index + e;
    float* h = (float*)d_out;         // [n,128], GRU state (fp32)

    char* w = (char*)d_ws;
    auto alloc = [&](size_t bytes) -> char* {
        char* p = w;
        w += (bytes + 255) & ~(size_t)255;
        return p;
    };
    int*   first_eid = (int*)  alloc((size_t)n * 4);
    int*   deg_cnt   = (int*)  alloc((size_t)n * 4);
    int*   row_ptr   = (int*)  alloc((size_t)(n + 1) * 4);
    int*   fill_ptr  = (int*)  alloc((size_t)n * 4);
    int*   tmp_scan  = (int*)  alloc((size_t)n * 4);
    int*   bsum      = (int*)  alloc((size_t)256 * 4);
    float* dis       = (float*)alloc((size_t)n * 4);
    float* norm_self = (float*)alloc((size_t)n * 4);
    int*   first_out = (int*)  alloc((size_t)n * 4);
    float* first_dx  = (float*)alloc((size_t)n * 4);
    int*   d1_of     = (int*)  alloc((size_t)n * 4);
    int*   d2_of     = (int*)  alloc((size_t)n * 4);
    float* dxb_of    = (float*)alloc((size_t)n * 4);
    int*   csr_src   = (int*)  alloc((size_t)e * 4);
    float* csr_w     = (float*)alloc((size_t)e * 4);
    // bf16 split weight transposes BT[n][k]
    u16* Wc1T_hi = (u16*)alloc((size_t)HID * 128 * 2);
    u16* Wc1T_lo = (u16*)alloc((size_t)HID * 128 * 2);
    u16* Wc2T_hi = (u16*)alloc((size_t)HID * 128 * 2);
    u16* Wc2T_lo = (u16*)alloc((size_t)HID * 128 * 2);
    u16* WihT_hi = (u16*)alloc((size_t)H3 * 128 * 2);
    u16* WihT_lo = (u16*)alloc((size_t)H3 * 128 * 2);
    u16* WhhT_hi = (u16*)alloc((size_t)H3 * 128 * 2);
    u16* WhhT_lo = (u16*)alloc((size_t)H3 * 128 * 2);
    // activations
    u16*   g_hi  = (u16*)  alloc((size_t)n * HID * 2);
    u16*   g_lo  = (u16*)  alloc((size_t)n * HID * 2);
    u16*   h_hi  = (u16*)  alloc((size_t)n * HID * 2);   // adjacent to h_lo (sizes 256-aligned)
    u16*   h_lo  = (u16*)  alloc((size_t)n * HID * 2);
    float* bufH  = (float*)alloc((size_t)n * HID * 4);
    u16*   bufHb = (u16*)  alloc((size_t)n * HID * 2);

    const int TPB = 256;
    const int nb = (n + 255) / 256;
    dim3 gN(nb), gE((e + TPB - 1) / TPB);

    // preprocessing (time-invariant)
    init_kernel<<<gN, TPB, 0, stream>>>(first_eid, deg_cnt, n);
    edge_pass1<<<gE, TPB, 0, stream>>>(src, dst, first_eid, deg_cnt, e);
    scan1<<<gN, TPB, 0, stream>>>(deg_cnt, tmp_scan, bsum, n);
    scan2<<<1, TPB, 0, stream>>>(bsum, nb);
    scan3<<<gN, TPB, 0, stream>>>(deg_cnt, tmp_scan, bsum, row_ptr, fill_ptr, dis, norm_self, n);
    firsts_kernel<<<gN, TPB, 0, stream>>>(first_eid, dst, edge_attr, first_out, first_dx, n, e);
    edge_pass2<<<gE, TPB, 0, stream>>>(src, dst, fill_ptr, dis, csr_src, csr_w, e);
    ghost_kernel<<<gN, TPB, 0, stream>>>(mask, first_out, first_dx, d1_of, d2_of, dxb_of, n);
    wsplit_kernel<<<dim3(HID / 32, 4), TPB, 0, stream>>>(Wc1, Wc1T_hi, Wc1T_lo, HID);
    wsplit_kernel<<<dim3(HID / 32, 4), TPB, 0, stream>>>(Wc2, Wc2T_hi, Wc2T_lo, HID);
    wsplit_kernel<<<dim3(H3 / 32, 4), TPB, 0, stream>>>(W_ih, WihT_hi, WihT_lo, H3);
    wsplit_kernel<<<dim3(H3 / 32, 4), TPB, 0, stream>>>(W_hh, WhhT_hi, WhhT_lo, H3);

    // h0 = 0 (fp32) and split hi/lo (adjacent region, as u32 words)
    zero2_kernel<<<2048, TPB, 0, stream>>>(h, n * HID, (unsigned*)h_hi, n * HID);

    dim3 grid_gcn((n + 63) / 64, 1, 1);
    dim3 agg_grid((n + 7) / 8);
    const int gru_blocks = (n + 15) / 16;

    for (int t = 0; t < T_IN; ++t) {
        fuse_lin_kernel<<<n, 128, 0, stream>>>(x, mask, d1_of, d2_of, dxb_of,
                                               Wf1, bf1, Wf2, bf2, Wg1, bg1, Wg2, bg2,
                                               W_lin, b_lin, g_hi, g_lo, t);
        // GCN layer 1: hw = g@Wc1 (fp32 + bf16 copy); agg -> g (split)
        gemm_mfma<64, 1><<<grid_gcn, 256, 0, stream>>>(
            g_hi, g_lo, Wc1T_hi, Wc1T_lo, bufH, bufHb, n, HID);
        gcn_agg<<<agg_grid, 256, 0, stream>>>(bufH, bufHb, row_ptr, csr_src, csr_w,
                                              norm_self, bc1, g_hi, g_lo, n);
        // GCN layer 2
        gemm_mfma<64, 1><<<grid_gcn, 256, 0, stream>>>(
            g_hi, g_lo, Wc2T_hi, Wc2T_lo, bufH, bufHb, n, HID);
        gcn_agg<<<agg_grid, 256, 0, stream>>>(bufH, bufHb, row_ptr, csr_src, csr_w,
                                              norm_self, bc2, g_hi, g_lo, n);
        // fused GRU: both GEMMs + gates + h/h_hi/h_lo update, no gi/gh round-trip
        gru_fused<<<gru_blocks, 256, 0, stream>>>(g_hi, g_lo,
                                                  WihT_hi, WihT_lo, WhhT_hi, WhhT_lo,
                                                  b_ih, b_hh, h, h_hi, h_lo, n);
    }
}

// Round 7
// 945.054 us; speedup vs baseline: 1.4931x; 1.4931x over previous
//
#include <hip/hip_runtime.h>
#include <math.h>

// Problem constants (match reference)
#define NN 20000
#define T_IN 8
#define FEAT 16
#define HID 128
#define H3 384
#define FUSER_IN 49
#define FUSER_H 96
#define GATE_H 48
#define ALPHA 0.5f

typedef unsigned short u16;
typedef __attribute__((ext_vector_type(8))) short bf16x8_t;
typedef __attribute__((ext_vector_type(4))) float f32x4_t;

__device__ __forceinline__ float sigmoidf_(float v) { return 1.0f / (1.0f + expf(-v)); }

// bf16 round-to-nearest-even (finite values only)
__device__ __forceinline__ u16 f2b(float v) {
    unsigned u = __float_as_uint(v);
    unsigned r = (u + 0x7fffu + ((u >> 16) & 1u)) >> 16;
    return (u16)r;
}
__device__ __forceinline__ float b2f(u16 u) { return __uint_as_float(((unsigned)u) << 16); }

// ---------------- preprocessing ----------------

__global__ void init_kernel(int* first_eid, int* deg_cnt, int n) {
    int i = blockIdx.x * 256 + threadIdx.x;
    if (i < n) { first_eid[i] = 0x7fffffff; deg_cnt[i] = 0; }
}

__global__ void edge_pass1(const int* __restrict__ src, const int* __restrict__ dst,
                           int* first_eid, int* deg_cnt, int e) {
    int i = blockIdx.x * 256 + threadIdx.x;
    if (i < e) {
        atomicMin(&first_eid[src[i]], i);
        atomicAdd(&deg_cnt[dst[i]], 1);
    }
}

// 3-phase parallel prefix sum over cnt[n] (n <= 256*256)
__global__ void scan1(const int* __restrict__ cnt, int* tmp, int* bsum, int n) {
    __shared__ int buf[256];
    int tid = threadIdx.x;
    int i = blockIdx.x * 256 + tid;
    int v = (i < n) ? cnt[i] : 0;
    buf[tid] = v;
    __syncthreads();
    #pragma unroll
    for (int off = 1; off < 256; off <<= 1) {
        int t = (tid >= off) ? buf[tid - off] : 0;
        __syncthreads();
        buf[tid] += t;
        __syncthreads();
    }
    if (i < n) tmp[i] = buf[tid];
    if (tid == 255) bsum[blockIdx.x] = buf[255];
}

__global__ void scan2(int* bsum, int nb) {
    __shared__ int buf[256];
    int tid = threadIdx.x;
    int v = (tid < nb) ? bsum[tid] : 0;
    buf[tid] = v;
    __syncthreads();
    #pragma unroll
    for (int off = 1; off < 256; off <<= 1) {
        int t = (tid >= off) ? buf[tid - off] : 0;
        __syncthreads();
        buf[tid] += t;
        __syncthreads();
    }
    if (tid < nb) bsum[tid] = buf[tid];   // inclusive block sums
}

__global__ void scan3(const int* __restrict__ cnt, const int* __restrict__ tmp,
                      const int* __restrict__ bsum,
                      int* row_ptr, int* fill_ptr, float* dis, float* norm_self, int n) {
    int i = blockIdx.x * 256 + threadIdx.x;
    if (i >= n) return;
    int pre = (blockIdx.x > 0) ? bsum[blockIdx.x - 1] : 0;
    int incl = tmp[i] + pre;
    int v = cnt[i];
    row_ptr[i + 1] = incl;
    fill_ptr[i] = incl - v;
    float deg = (float)v + 1.0f;
    dis[i] = 1.0f / sqrtf(deg);
    norm_self[i] = 1.0f / deg;
    if (i == 0) row_ptr[0] = 0;
}

__global__ void firsts_kernel(const int* __restrict__ first_eid, const int* __restrict__ dst,
                              const float* __restrict__ edge_attr,
                              int* first_out, float* first_dx, int n, int e) {
    int i = blockIdx.x * 256 + threadIdx.x;
    if (i >= n) return;
    int fe = first_eid[i];
    if (fe < e) {
        first_out[i] = dst[fe];
        first_dx[i] = fmaxf(edge_attr[fe], 1e-6f);
    } else {
        first_out[i] = -1;
        first_dx[i] = -1.0f;
    }
}

__global__ void edge_pass2(const int* __restrict__ src, const int* __restrict__ dst,
                           int* fill_ptr, const float* __restrict__ dis,
                           int* csr_src, float* csr_w, int e) {
    int i = blockIdx.x * 256 + threadIdx.x;
    if (i < e) {
        int d = dst[i], s = src[i];
        int pos = atomicAdd(&fill_ptr[d], 1);
        csr_src[pos] = s;
        csr_w[pos] = dis[s] * dis[d];
    }
}

__global__ void ghost_kernel(const int* __restrict__ mask, const int* __restrict__ first_out,
                             const float* __restrict__ first_dx,
                             int* d1_of, int* d2_of, float* dxb_of, int n) {
    int i = blockIdx.x * 256 + threadIdx.x;
    if (i >= n || mask[i] != 0) return;
    int b = first_out[i];
    float dxb = fmaxf(first_dx[i], 1e-6f);
    int d1, d2;
    if (b < 0) { d1 = i; d2 = i; }
    else {
        int n1 = first_out[b]; d1 = (n1 < 0) ? b : n1;
        int n2 = first_out[d1]; d2 = (n2 < 0) ? d1 : n2;
    }
    d1_of[i] = d1; d2_of[i] = d2; dxb_of[i] = dxb;
}

// zero two regions in one dispatch (grid-stride)
__global__ void zero2_kernel(float* a, int na, unsigned* b, int nb) {
    int stride = gridDim.x * 256;
    for (int i = blockIdx.x * 256 + threadIdx.x; i < na; i += stride) a[i] = 0.0f;
    for (int i = blockIdx.x * 256 + threadIdx.x; i < nb; i += stride) b[i] = 0u;
}

// W[k][nn] (K=128) -> BT_hi/BT_lo[nn][k] bf16 split, LDS-tiled transpose (coalesced both sides)
__global__ __launch_bounds__(256)
void wsplit_kernel(const float* __restrict__ W, u16* BT_hi, u16* BT_lo, int Ncols) {
    __shared__ float tile[32][33];
    int nb = blockIdx.x * 32;           // column-of-W (=row-of-BT) base
    int kb = blockIdx.y * 32;           // k base
    int tx = threadIdx.x & 31, ty = threadIdx.x >> 5;   // 32 x 8
    #pragma unroll
    for (int r = 0; r < 32; r += 8)
        tile[ty + r][tx] = W[(size_t)(kb + ty + r) * Ncols + nb + tx];
    __syncthreads();
    #pragma unroll
    for (int r = 0; r < 32; r += 8) {
        float v = tile[tx][ty + r];     // = W[kb+tx][nb+ty+r]
        u16 h = f2b(v);
        size_t off = (size_t)(nb + ty + r) * 128 + kb + tx;
        BT_hi[off] = h;
        BT_lo[off] = f2b(v - b2f(h));
    }
}

// ---------------- batched front-end kernels (independent of h; all t at once) ----------------

// One block (128 threads) per (node, t): ghost fusion + g = relu(x_fused @ W_lin + b_lin)
// blockIdx.y = t. Output g8[t][node][128] bf16 hi/lo.
__global__ __launch_bounds__(128)
void fuse_lin_all(const float* __restrict__ x, const int* __restrict__ mask,
                  const int* __restrict__ d1_of, const int* __restrict__ d2_of,
                  const float* __restrict__ dxb_of,
                  const float* __restrict__ Wf1, const float* __restrict__ bf1,
                  const float* __restrict__ Wf2, const float* __restrict__ bf2,
                  const float* __restrict__ Wg1, const float* __restrict__ bg1,
                  const float* __restrict__ Wg2, const float* __restrict__ bg2,
                  const float* __restrict__ W_lin, const float* __restrict__ b_lin,
                  u16* __restrict__ g8_hi, u16* __restrict__ g8_lo, int n) {
    int i = blockIdx.x;
    int t = blockIdx.y;
    int j = threadIdx.x;
    __shared__ float feats[FUSER_IN];
    __shared__ float xf[FEAT];
    __shared__ float z1[FUSER_H];
    __shared__ float zg[GATE_H];
    __shared__ float s_gate;

    const float* xrow = &x[(i * T_IN + t) * FEAT];
    if (j < FEAT) { float v = xrow[j]; feats[j] = v; xf[j] = v; }

    bool ghost = (mask[i] == 0);
    if (ghost) {
        if (j < FEAT) {
            int d1 = d1_of[i], d2 = d2_of[i];
            feats[FEAT + j]     = x[(d1 * T_IN + t) * FEAT + j];
            feats[2 * FEAT + j] = x[(d2 * T_IN + t) * FEAT + j];
        }
        if (j == 0) feats[3 * FEAT] = dxb_of[i];
        __syncthreads();
        if (j < FUSER_H) {
            float acc = bf1[j];
            for (int k = 0; k < FUSER_IN; ++k) acc = fmaf(feats[k], Wf1[k * FUSER_H + j], acc);
            z1[j] = fmaxf(acc, 0.0f);
        }
        if (j < GATE_H) {
            float acc = bg1[j];
            for (int k = 0; k < FUSER_IN; ++k) acc = fmaf(feats[k], Wg1[k * GATE_H + j], acc);
            zg[j] = fmaxf(acc, 0.0f);
        }
        __syncthreads();
        if (j == 0) {
            float s = bg2[0];
            for (int k = 0; k < GATE_H; ++k) s = fmaf(zg[k], Wg2[k], s);
            s_gate = sigmoidf_(s);
        }
        __syncthreads();
        if (j < FEAT) {
            float acc = bf2[j];
            for (int k = 0; k < FUSER_H; ++k) acc = fmaf(z1[k], Wf2[k * FEAT + j], acc);
            xf[j] = feats[j] + ALPHA * acc * s_gate;
        }
    }
    __syncthreads();
    float acc = b_lin[j];
    #pragma unroll
    for (int k = 0; k < FEAT; ++k) acc = fmaf(xf[k], W_lin[k * HID + j], acc);
    float v = fmaxf(acc, 0.0f);
    u16 hv = f2b(v);
    size_t off = ((size_t)t * n + i) * HID + j;
    g8_hi[off] = hv;
    g8_lo[off] = f2b(v - b2f(hv));
}

// Batched GCN GEMM: C[t][M x 128] = A[t][M x 128] @ B[128 x 128], bf16x3 MFMA.
// BM=64, 4 waves (2x2). K=128 in LDS (XOR-swizzled). blockIdx.z = t.
// Writes fp32 C and bf16 copy Cb.
__global__ __launch_bounds__(256)
void gemm_gcn_b(const u16* __restrict__ Ahi0, const u16* __restrict__ Alo0,
                const u16* __restrict__ BThi, const u16* __restrict__ BTlo,
                float* __restrict__ C0, u16* __restrict__ Cb0, int M) {
    constexpr int BM = 64;
    __shared__ u16 ldsA[2][BM * 128];
    const size_t tOff = (size_t)blockIdx.z * M * 128;
    const u16* Ahi = Ahi0 + tOff;
    const u16* Alo = Alo0 + tOff;
    float*     C   = C0 + tOff;
    u16*       Cb  = Cb0 + tOff;

    const int tid  = threadIdx.x;
    const int row0 = blockIdx.x * BM;
    constexpr int MF = BM / 32;

    #pragma unroll
    for (int it = 0; it < BM / 16; ++it) {
        int unit = tid + it * 256;
        int r = unit >> 4, s = unit & 15;
        int gr = row0 + r;
        uint4 vh = make_uint4(0, 0, 0, 0), vl = vh;
        if (gr < M) {
            vh = *reinterpret_cast<const uint4*>(&Ahi[(size_t)gr * 128 + s * 8]);
            vl = *reinterpret_cast<const uint4*>(&Alo[(size_t)gr * 128 + s * 8]);
        }
        int byte = (r * 256 + s * 16) ^ ((r & 7) << 4);
        *reinterpret_cast<uint4*>((char*)(&ldsA[0][0]) + byte) = vh;
        *reinterpret_cast<uint4*>((char*)(&ldsA[1][0]) + byte) = vl;
    }
    __syncthreads();

    const int wid  = tid >> 6;
    const int lane = tid & 63;
    const int wr = (wid >> 1) * (BM / 2);
    const int wc = (wid & 1) * 64;
    const int l15 = lane & 15;
    const int lkh = lane >> 4;

    f32x4_t acc[MF][4] = {};

    #pragma unroll
    for (int kb = 0; kb < 4; ++kb) {
        bf16x8_t ah[MF], al[MF], bh[4], bl[4];
        #pragma unroll
        for (int m = 0; m < MF; ++m) {
            int row = wr + m * 16 + l15;
            int byte = (row * 256 + kb * 64 + lkh * 16) ^ ((row & 7) << 4);
            ah[m] = *reinterpret_cast<const bf16x8_t*>((const char*)(&ldsA[0][0]) + byte);
            al[m] = *reinterpret_cast<const bf16x8_t*>((const char*)(&ldsA[1][0]) + byte);
        }
        #pragma unroll
        for (int nf = 0; nf < 4; ++nf) {
            int col = wc + nf * 16 + l15;
            size_t off = (size_t)col * 128 + kb * 32 + lkh * 8;
            bh[nf] = *reinterpret_cast<const bf16x8_t*>(&BThi[off]);
            bl[nf] = *reinterpret_cast<const bf16x8_t*>(&BTlo[off]);
        }
        #pragma unroll
        for (int m = 0; m < MF; ++m)
            #pragma unroll
            for (int nf = 0; nf < 4; ++nf) {
                acc[m][nf] = __builtin_amdgcn_mfma_f32_16x16x32_bf16(ah[m], bh[nf], acc[m][nf], 0, 0, 0);
                acc[m][nf] = __builtin_amdgcn_mfma_f32_16x16x32_bf16(ah[m], bl[nf], acc[m][nf], 0, 0, 0);
                acc[m][nf] = __builtin_amdgcn_mfma_f32_16x16x32_bf16(al[m], bh[nf], acc[m][nf], 0, 0, 0);
            }
    }

    #pragma unroll
    for (int m = 0; m < MF; ++m) {
        int rbase = row0 + wr + m * 16 + lkh * 4;
        #pragma unroll
        for (int nf = 0; nf < 4; ++nf) {
            int col = wc + nf * 16 + l15;
            #pragma unroll
            for (int r2 = 0; r2 < 4; ++r2) {
                int row = rbase + r2;
                if (row < M) {
                    float v = acc[m][nf][r2];
                    C[(size_t)row * 128 + col] = v;
                    Cb[(size_t)row * 128 + col] = f2b(v);
                }
            }
        }
    }
}

// Batched GCN aggregate: blockIdx.y = t. 32 threads/node, ushort4 gathers.
__global__ __launch_bounds__(256)
void gcn_agg_b(const float* __restrict__ hw0, const u16* __restrict__ hwb0,
               const int* __restrict__ row_ptr,
               const int* __restrict__ csr_src, const float* __restrict__ csr_w,
               const float* __restrict__ norm_self, const float* __restrict__ bias,
               u16* __restrict__ g_hi0, u16* __restrict__ g_lo0, int n) {
    int node = blockIdx.x * 8 + (threadIdx.x >> 5);
    int lane = threadIdx.x & 31;
    if (node >= n) return;
    const size_t tOff = (size_t)blockIdx.y * n * 128;
    const float* hw  = hw0 + tOff;
    const u16*   hwb = hwb0 + tOff;
    u16* g_hi = g_hi0 + tOff;
    u16* g_lo = g_lo0 + tOff;

    const float4* hw4 = reinterpret_cast<const float4*>(hw);
    float4 self = hw4[(size_t)node * 32 + lane];
    float ns = norm_self[node];
    float4 a0, a1, a2, a3;
    a0.x = self.x * ns; a0.y = self.y * ns; a0.z = self.z * ns; a0.w = self.w * ns;
    a1 = make_float4(0.f, 0.f, 0.f, 0.f); a2 = a1; a3 = a1;
    int p  = row_ptr[node];
    int p1 = row_ptr[node + 1];
    for (; p + 4 <= p1; p += 4) {
        int s0 = csr_src[p], s1 = csr_src[p + 1], s2 = csr_src[p + 2], s3 = csr_src[p + 3];
        float w0 = csr_w[p], w1 = csr_w[p + 1], w2 = csr_w[p + 2], w3 = csr_w[p + 3];
        ushort4 v0 = *reinterpret_cast<const ushort4*>(&hwb[(size_t)s0 * HID + lane * 4]);
        ushort4 v1 = *reinterpret_cast<const ushort4*>(&hwb[(size_t)s1 * HID + lane * 4]);
        ushort4 v2 = *reinterpret_cast<const ushort4*>(&hwb[(size_t)s2 * HID + lane * 4]);
        ushort4 v3 = *reinterpret_cast<const ushort4*>(&hwb[(size_t)s3 * HID + lane * 4]);
        a0.x = fmaf(b2f(v0.x), w0, a0.x); a0.y = fmaf(b2f(v0.y), w0, a0.y);
        a0.z = fmaf(b2f(v0.z), w0, a0.z); a0.w = fmaf(b2f(v0.w), w0, a0.w);
        a1.x = fmaf(b2f(v1.x), w1, a1.x); a1.y = fmaf(b2f(v1.y), w1, a1.y);
        a1.z = fmaf(b2f(v1.z), w1, a1.z); a1.w = fmaf(b2f(v1.w), w1, a1.w);
        a2.x = fmaf(b2f(v2.x), w2, a2.x); a2.y = fmaf(b2f(v2.y), w2, a2.y);
        a2.z = fmaf(b2f(v2.z), w2, a2.z); a2.w = fmaf(b2f(v2.w), w2, a2.w);
        a3.x = fmaf(b2f(v3.x), w3, a3.x); a3.y = fmaf(b2f(v3.y), w3, a3.y);
        a3.z = fmaf(b2f(v3.z), w3, a3.z); a3.w = fmaf(b2f(v3.w), w3, a3.w);
    }
    for (; p < p1; ++p) {
        int s = csr_src[p];
        float w = csr_w[p];
        ushort4 v = *reinterpret_cast<const ushort4*>(&hwb[(size_t)s * HID + lane * 4]);
        a0.x = fmaf(b2f(v.x), w, a0.x); a0.y = fmaf(b2f(v.y), w, a0.y);
        a0.z = fmaf(b2f(v.z), w, a0.z); a0.w = fmaf(b2f(v.w), w, a0.w);
    }
    float4 b4 = reinterpret_cast<const float4*>(bias)[lane];
    float ox = fmaxf(a0.x + a1.x + a2.x + a3.x + b4.x, 0.0f);
    float oy = fmaxf(a0.y + a1.y + a2.y + a3.y + b4.y, 0.0f);
    float oz = fmaxf(a0.z + a1.z + a2.z + a3.z + b4.z, 0.0f);
    float ow = fmaxf(a0.w + a1.w + a2.w + a3.w + b4.w, 0.0f);
    ushort4 hv, lv;
    hv.x = f2b(ox); lv.x = f2b(ox - b2f(hv.x));
    hv.y = f2b(oy); lv.y = f2b(oy - b2f(hv.y));
    hv.z = f2b(oz); lv.z = f2b(oz - b2f(hv.z));
    hv.w = f2b(ow); lv.w = f2b(ow - b2f(hv.w));
    *reinterpret_cast<ushort4*>(&g_hi[(size_t)node * HID + lane * 4]) = hv;
    *reinterpret_cast<ushort4*>(&g_lo[(size_t)node * HID + lane * 4]) = lv;
}

// ---------------- sequential GRU kernels (R5-proven structure) ----------------

// Dual GEMM: blockIdx.z=0 -> C1 = A1@B1 (gi), z=1 -> C2 = A2@B2 (gh). BM=128, BN=128.
__global__ __launch_bounds__(256)
void gemm_gru(const u16* __restrict__ Ahi1, const u16* __restrict__ Alo1,
              const u16* __restrict__ BThi1, const u16* __restrict__ BTlo1,
              float* __restrict__ C1,
              const u16* __restrict__ Ahi2, const u16* __restrict__ Alo2,
              const u16* __restrict__ BThi2, const u16* __restrict__ BTlo2,
              float* __restrict__ C2,
              int M, int Ncols) {
    constexpr int BM = 128;
    __shared__ u16 ldsA[2][BM * 128];
    const u16* Ahi  = blockIdx.z ? Ahi2  : Ahi1;
    const u16* Alo  = blockIdx.z ? Alo2  : Alo1;
    const u16* BThi = blockIdx.z ? BThi2 : BThi1;
    const u16* BTlo = blockIdx.z ? BTlo2 : BTlo1;
    float*     C    = blockIdx.z ? C2    : C1;

    const int tid  = threadIdx.x;
    const int row0 = blockIdx.x * BM;
    const int col0 = blockIdx.y * 128;
    constexpr int MF = BM / 32;

    #pragma unroll
    for (int it = 0; it < BM / 16; ++it) {
        int unit = tid + it * 256;
        int r = unit >> 4, s = unit & 15;
        int gr = row0 + r;
        uint4 vh = make_uint4(0, 0, 0, 0), vl = vh;
        if (gr < M) {
            vh = *reinterpret_cast<const uint4*>(&Ahi[(size_t)gr * 128 + s * 8]);
            vl = *reinterpret_cast<const uint4*>(&Alo[(size_t)gr * 128 + s * 8]);
        }
        int byte = (r * 256 + s * 16) ^ ((r & 7) << 4);
        *reinterpret_cast<uint4*>((char*)(&ldsA[0][0]) + byte) = vh;
        *reinterpret_cast<uint4*>((char*)(&ldsA[1][0]) + byte) = vl;
    }
    __syncthreads();

    const int wid  = tid >> 6;
    const int lane = tid & 63;
    const int wr = (wid >> 1) * (BM / 2);
    const int wc = (wid & 1) * 64;
    const int l15 = lane & 15;
    const int lkh = lane >> 4;

    f32x4_t acc[MF][4] = {};

    #pragma unroll
    for (int kb = 0; kb < 4; ++kb) {
        bf16x8_t ah[MF], al[MF], bh[4], bl[4];
        #pragma unroll
        for (int m = 0; m < MF; ++m) {
            int row = wr + m * 16 + l15;
            int byte = (row * 256 + kb * 64 + lkh * 16) ^ ((row & 7) << 4);
            ah[m] = *reinterpret_cast<const bf16x8_t*>((const char*)(&ldsA[0][0]) + byte);
            al[m] = *reinterpret_cast<const bf16x8_t*>((const char*)(&ldsA[1][0]) + byte);
        }
        #pragma unroll
        for (int nf = 0; nf < 4; ++nf) {
            int col = col0 + wc + nf * 16 + l15;
            size_t off = (size_t)col * 128 + kb * 32 + lkh * 8;
            bh[nf] = *reinterpret_cast<const bf16x8_t*>(&BThi[off]);
            bl[nf] = *reinterpret_cast<const bf16x8_t*>(&BTlo[off]);
        }
        #pragma unroll
        for (int m = 0; m < MF; ++m)
            #pragma unroll
            for (int nf = 0; nf < 4; ++nf) {
                acc[m][nf] = __builtin_amdgcn_mfma_f32_16x16x32_bf16(ah[m], bh[nf], acc[m][nf], 0, 0, 0);
                acc[m][nf] = __builtin_amdgcn_mfma_f32_16x16x32_bf16(ah[m], bl[nf], acc[m][nf], 0, 0, 0);
                acc[m][nf] = __builtin_amdgcn_mfma_f32_16x16x32_bf16(al[m], bh[nf], acc[m][nf], 0, 0, 0);
            }
    }

    #pragma unroll
    for (int m = 0; m < MF; ++m) {
        int rbase = row0 + wr + m * 16 + lkh * 4;
        #pragma unroll
        for (int nf = 0; nf < 4; ++nf) {
            int col = col0 + wc + nf * 16 + l15;
            #pragma unroll
            for (int r2 = 0; r2 < 4; ++r2) {
                int row = rbase + r2;
                if (row < M) C[(size_t)row * Ncols + col] = acc[m][nf][r2];
            }
        }
    }
}

__global__ __launch_bounds__(256)
void gru_kernel(const float* __restrict__ gi, const float* __restrict__ gh,
                const float* __restrict__ b_ih, const float* __restrict__ b_hh,
                float* __restrict__ h, u16* __restrict__ h_hi, u16* __restrict__ h_lo, int n) {
    int idx = blockIdx.x * 256 + threadIdx.x;     // one float4 of h per thread
    if (idx >= n * 32) return;
    int row = idx >> 5, q = idx & 31;
    const float4* gi4 = reinterpret_cast<const float4*>(gi + (size_t)row * H3);
    const float4* gh4 = reinterpret_cast<const float4*>(gh + (size_t)row * H3);
    const float4* bi4 = reinterpret_cast<const float4*>(b_ih);
    const float4* bh4 = reinterpret_cast<const float4*>(b_hh);
    float4 vir = gi4[q], viz = gi4[32 + q], vin = gi4[64 + q];
    float4 vhr = gh4[q], vhz = gh4[32 + q], vhn = gh4[64 + q];
    float4 bir = bi4[q], biz = bi4[32 + q], bin_ = bi4[64 + q];
    float4 bhr = bh4[q], bhz = bh4[32 + q], bhn = bh4[64 + q];
    float4* h4 = reinterpret_cast<float4*>(h);
    float4 hv = h4[idx];
    float4 o;
    {
        float r = sigmoidf_((vir.x + bir.x) + (vhr.x + bhr.x));
        float z = sigmoidf_((viz.x + biz.x) + (vhz.x + bhz.x));
        float nn2 = tanhf((vin.x + bin_.x) + r * (vhn.x + bhn.x));
        o.x = (1.0f - z) * nn2 + z * hv.x;
    }
    {
        float r = sigmoidf_((vir.y + bir.y) + (vhr.y + bhr.y));
        float z = sigmoidf_((viz.y + biz.y) + (vhz.y + bhz.y));
        float nn2 = tanhf((vin.y + bin_.y) + r * (vhn.y + bhn.y));
        o.y = (1.0f - z) * nn2 + z * hv.y;
    }
    {
        float r = sigmoidf_((vir.z + bir.z) + (vhr.z + bhr.z));
        float z = sigmoidf_((viz.z + biz.z) + (vhz.z + bhz.z));
        float nn2 = tanhf((vin.z + bin_.z) + r * (vhn.z + bhn.z));
        o.z = (1.0f - z) * nn2 + z * hv.z;
    }
    {
        float r = sigmoidf_((vir.w + bir.w) + (vhr.w + bhr.w));
        float z = sigmoidf_((viz.w + biz.w) + (vhz.w + bhz.w));
        float nn2 = tanhf((vin.w + bin_.w) + r * (vhn.w + bhn.w));
        o.w = (1.0f - z) * nn2 + z * hv.w;
    }
    h4[idx] = o;
    ushort4 hvv, lvv;
    hvv.x = f2b(o.x); lvv.x = f2b(o.x - b2f(hvv.x));
    hvv.y = f2b(o.y); lvv.y = f2b(o.y - b2f(hvv.y));
    hvv.z = f2b(o.z); lvv.z = f2b(o.z - b2f(hvv.z));
    hvv.w = f2b(o.w); lvv.w = f2b(o.w - b2f(hvv.w));
    *reinterpret_cast<ushort4*>(&h_hi[(size_t)row * HID + q * 4]) = hvv;
    *reinterpret_cast<ushort4*>(&h_lo[(size_t)row * HID + q * 4]) = lvv;
}

// ---------------- launcher ----------------

extern "C" void kernel_launch(void* const* d_in, const int* in_sizes, int n_in,
                              void* d_out, int out_size, void* d_ws, size_t ws_size,
                              hipStream_t stream) {
    const float* x        = (const float*)d_in[0];
    const float* edge_attr= (const float*)d_in[1];
    const float* W_lin    = (const float*)d_in[2];
    const float* b_lin    = (const float*)d_in[3];
    const float* Wc1      = (const float*)d_in[4];
    const float* bc1      = (const float*)d_in[5];
    const float* Wc2      = (const float*)d_in[6];
    const float* bc2      = (const float*)d_in[7];
    const float* W_ih     = (const float*)d_in[8];
    const float* b_ih     = (const float*)d_in[9];
    const float* W_hh     = (const float*)d_in[10];
    const float* b_hh     = (const float*)d_in[11];
    const float* Wf1      = (const float*)d_in[12];
    const float* bf1      = (const float*)d_in[13];
    const float* Wf2      = (const float*)d_in[14];
    const float* bf2      = (const float*)d_in[15];
    const float* Wg1      = (const float*)d_in[16];
    const float* bg1      = (const float*)d_in[17];
    const float* Wg2      = (const float*)d_in[18];
    const float* bg2      = (const float*)d_in[19];
    const int*   edge_index = (const int*)d_in[20];
    const int*   mask     = (const int*)d_in[21];

    const int n = in_sizes[21];       // 20000
    const int e = in_sizes[1];        // 320000
    const int* src = edge_index;
    const int* dst = edge_index + e;
    float* h = (float*)d_out;         // [n,128], GRU state (fp32)

    char* w = (char*)d_ws;
    auto alloc = [&](size_t bytes) -> char* {
        char* p = w;
        w += (bytes + 255) & ~(size_t)255;
        return p;
    };
    int*   first_eid = (int*)  alloc((size_t)n * 4);
    int*   deg_cnt   = (int*)  alloc((size_t)n * 4);
    int*   row_ptr   = (int*)  alloc((size_t)(n + 1) * 4);
    int*   fill_ptr  = (int*)  alloc((size_t)n * 4);
    int*   tmp_scan  = (int*)  alloc((size_t)n * 4);
    int*   bsum      = (int*)  alloc((size_t)256 * 4);
    float* dis       = (float*)alloc((size_t)n * 4);
    float* norm_self = (float*)alloc((size_t)n * 4);
    int*   first_out = (int*)  alloc((size_t)n * 4);
    float* first_dx  = (float*)alloc((size_t)n * 4);
    int*   d1_of     = (int*)  alloc((size_t)n * 4);
    int*   d2_of     = (int*)  alloc((size_t)n * 4);
    float* dxb_of    = (float*)alloc((size_t)n * 4);
    int*   csr_src   = (int*)  alloc((size_t)e * 4);
    float* csr_w     = (float*)alloc((size_t)e * 4);
    // bf16 split weight transposes BT[n][k]
    u16* Wc1T_hi = (u16*)alloc((size_t)HID * 128 * 2);
    u16* Wc1T_lo = (u16*)alloc((size_t)HID * 128 * 2);
    u16* Wc2T_hi = (u16*)alloc((size_t)HID * 128 * 2);
    u16* Wc2T_lo = (u16*)alloc((size_t)HID * 128 * 2);
    u16* WihT_hi = (u16*)alloc((size_t)H3 * 128 * 2);
    u16* WihT_lo = (u16*)alloc((size_t)H3 * 128 * 2);
    u16* WhhT_hi = (u16*)alloc((size_t)H3 * 128 * 2);
    u16* WhhT_lo = (u16*)alloc((size_t)H3 * 128 * 2);
    // activations (batched over all T_IN)
    u16*   g8_hi = (u16*)  alloc((size_t)T_IN * n * HID * 2);   // 41 MB
    u16*   g8_lo = (u16*)  alloc((size_t)T_IN * n * HID * 2);   // 41 MB
    float* bufH  = (float*)alloc((size_t)T_IN * n * HID * 4);   // 82 MB (reused as gi/gh in phase B)
    u16*   bufHb = (u16*)  alloc((size_t)T_IN * n * HID * 2);   // 41 MB
    u16*   h_hi  = (u16*)  alloc((size_t)n * HID * 2);
    u16*   h_lo  = (u16*)  alloc((size_t)n * HID * 2);

    float* bufGi = bufH;                          // [n][384] fp32, phase B only
    float* bufGh = bufH + (size_t)n * H3;

    const int TPB = 256;
    const int nb = (n + 255) / 256;
    dim3 gN(nb), gE((e + TPB - 1) / TPB);

    // preprocessing (time-invariant)
    init_kernel<<<gN, TPB, 0, stream>>>(first_eid, deg_cnt, n);
    edge_pass1<<<gE, TPB, 0, stream>>>(src, dst, first_eid, deg_cnt, e);
    scan1<<<gN, TPB, 0, stream>>>(deg_cnt, tmp_scan, bsum, n);
    scan2<<<1, TPB, 0, stream>>>(bsum, nb);
    scan3<<<gN, TPB, 0, stream>>>(deg_cnt, tmp_scan, bsum, row_ptr, fill_ptr, dis, norm_self, n);
    firsts_kernel<<<gN, TPB, 0, stream>>>(first_eid, dst, edge_attr, first_out, first_dx, n, e);
    edge_pass2<<<gE, TPB, 0, stream>>>(src, dst, fill_ptr, dis, csr_src, csr_w, e);
    ghost_kernel<<<gN, TPB, 0, stream>>>(mask, first_out, first_dx, d1_of, d2_of, dxb_of, n);
    wsplit_kernel<<<dim3(HID / 32, 4), TPB, 0, stream>>>(Wc1, Wc1T_hi, Wc1T_lo, HID);
    wsplit_kernel<<<dim3(HID / 32, 4), TPB, 0, stream>>>(Wc2, Wc2T_hi, Wc2T_lo, HID);
    wsplit_kernel<<<dim3(H3 / 32, 4), TPB, 0, stream>>>(W_ih, WihT_hi, WihT_lo, H3);
    wsplit_kernel<<<dim3(H3 / 32, 4), TPB, 0, stream>>>(W_hh, WhhT_hi, WhhT_lo, H3);

    // h0 = 0 (fp32) and split hi/lo (adjacent region, as u32 words)
    zero2_kernel<<<2048, TPB, 0, stream>>>(h, n * HID, (unsigned*)h_hi, n * HID);

    // ---- Phase A: front end for ALL timesteps (independent of h) ----
    dim3 grid_fuse(n, T_IN);
    dim3 grid_gcn((n + 63) / 64, 1, T_IN);
    dim3 grid_agg((n + 7) / 8, T_IN);

    fuse_lin_all<<<grid_fuse, 128, 0, stream>>>(x, mask, d1_of, d2_of, dxb_of,
                                                Wf1, bf1, Wf2, bf2, Wg1, bg1, Wg2, bg2,
                                                W_lin, b_lin, g8_hi, g8_lo, n);
    gemm_gcn_b<<<grid_gcn, 256, 0, stream>>>(g8_hi, g8_lo, Wc1T_hi, Wc1T_lo, bufH, bufHb, n);
    gcn_agg_b<<<grid_agg, 256, 0, stream>>>(bufH, bufHb, row_ptr, csr_src, csr_w,
                                            norm_self, bc1, g8_hi, g8_lo, n);
    gemm_gcn_b<<<grid_gcn, 256, 0, stream>>>(g8_hi, g8_lo, Wc2T_hi, Wc2T_lo, bufH, bufHb, n);
    gcn_agg_b<<<grid_agg, 256, 0, stream>>>(bufH, bufHb, row_ptr, csr_src, csr_w,
                                            norm_self, bc2, g8_hi, g8_lo, n);

    // ---- Phase B: sequential GRU over timesteps ----
    dim3 grid_gru((n + 127) / 128, 3, 2);
    for (int t = 0; t < T_IN; ++t) {
        const u16* Gt_hi = g8_hi + (size_t)t * n * HID;
        const u16* Gt_lo = g8_lo + (size_t)t * n * HID;
        gemm_gru<<<grid_gru, 256, 0, stream>>>(
            Gt_hi, Gt_lo, WihT_hi, WihT_lo, bufGi,
            h_hi, h_lo, WhhT_hi, WhhT_lo, bufGh, n, H3);
        gru_kernel<<<(n * 32 + TPB - 1) / TPB, TPB, 0, stream>>>(bufGi, bufGh, b_ih, b_hh,
                                                                 h, h_hi, h_lo, n);
    }
}

// Round 8
// 937.995 us; speedup vs baseline: 1.5044x; 1.0075x over previous
//
#include <hip/hip_runtime.h>
#include <math.h>

// Problem constants (match reference)
#define NN 20000
#define T_IN 8
#define FEAT 16
#define HID 128
#define H3 384
#define FUSER_IN 49
#define FUSER_H 96
#define GATE_H 48
#define ALPHA 0.5f

typedef unsigned short u16;
typedef __attribute__((ext_vector_type(8))) short bf16x8_t;
typedef __attribute__((ext_vector_type(4))) float f32x4_t;

__device__ __forceinline__ float sigmoidf_(float v) { return 1.0f / (1.0f + expf(-v)); }

// bf16 round-to-nearest-even (finite values only)
__device__ __forceinline__ u16 f2b(float v) {
    unsigned u = __float_as_uint(v);
    unsigned r = (u + 0x7fffu + ((u >> 16) & 1u)) >> 16;
    return (u16)r;
}
__device__ __forceinline__ float b2f(u16 u) { return __uint_as_float(((unsigned)u) << 16); }

// ---------------- preprocessing ----------------

__global__ void init_kernel(int* first_eid, int* deg_cnt, int* gcount, int n) {
    int i = blockIdx.x * 256 + threadIdx.x;
    if (i < n) { first_eid[i] = 0x7fffffff; deg_cnt[i] = 0; }
    if (i == 0) *gcount = 0;
}

__global__ void edge_pass1(const int* __restrict__ src, const int* __restrict__ dst,
                           int* first_eid, int* deg_cnt, int e) {
    int i = blockIdx.x * 256 + threadIdx.x;
    if (i < e) {
        atomicMin(&first_eid[src[i]], i);
        atomicAdd(&deg_cnt[dst[i]], 1);
    }
}

// 3-phase parallel prefix sum over cnt[n] (n <= 256*256)
__global__ void scan1(const int* __restrict__ cnt, int* tmp, int* bsum, int n) {
    __shared__ int buf[256];
    int tid = threadIdx.x;
    int i = blockIdx.x * 256 + tid;
    int v = (i < n) ? cnt[i] : 0;
    buf[tid] = v;
    __syncthreads();
    #pragma unroll
    for (int off = 1; off < 256; off <<= 1) {
        int t = (tid >= off) ? buf[tid - off] : 0;
        __syncthreads();
        buf[tid] += t;
        __syncthreads();
    }
    if (i < n) tmp[i] = buf[tid];
    if (tid == 255) bsum[blockIdx.x] = buf[255];
}

__global__ void scan2(int* bsum, int nb) {
    __shared__ int buf[256];
    int tid = threadIdx.x;
    int v = (tid < nb) ? bsum[tid] : 0;
    buf[tid] = v;
    __syncthreads();
    #pragma unroll
    for (int off = 1; off < 256; off <<= 1) {
        int t = (tid >= off) ? buf[tid - off] : 0;
        __syncthreads();
        buf[tid] += t;
        __syncthreads();
    }
    if (tid < nb) bsum[tid] = buf[tid];   // inclusive block sums
}

__global__ void scan3(const int* __restrict__ cnt, const int* __restrict__ tmp,
                      const int* __restrict__ bsum,
                      int* row_ptr, int* fill_ptr, float* dis, float* norm_self, int n) {
    int i = blockIdx.x * 256 + threadIdx.x;
    if (i >= n) return;
    int pre = (blockIdx.x > 0) ? bsum[blockIdx.x - 1] : 0;
    int incl = tmp[i] + pre;
    int v = cnt[i];
    row_ptr[i + 1] = incl;
    fill_ptr[i] = incl - v;
    float deg = (float)v + 1.0f;
    dis[i] = 1.0f / sqrtf(deg);
    norm_self[i] = 1.0f / deg;
    if (i == 0) row_ptr[0] = 0;
}

__global__ void firsts_kernel(const int* __restrict__ first_eid, const int* __restrict__ dst,
                              const float* __restrict__ edge_attr,
                              int* first_out, float* first_dx, int n, int e) {
    int i = blockIdx.x * 256 + threadIdx.x;
    if (i >= n) return;
    int fe = first_eid[i];
    if (fe < e) {
        first_out[i] = dst[fe];
        first_dx[i] = fmaxf(edge_attr[fe], 1e-6f);
    } else {
        first_out[i] = -1;
        first_dx[i] = -1.0f;
    }
}

__global__ void edge_pass2(const int* __restrict__ src, const int* __restrict__ dst,
                           int* fill_ptr, const float* __restrict__ dis,
                           int* csr_src, float* csr_w, int e) {
    int i = blockIdx.x * 256 + threadIdx.x;
    if (i < e) {
        int d = dst[i], s = src[i];
        int pos = atomicAdd(&fill_ptr[d], 1);
        csr_src[pos] = s;
        csr_w[pos] = dis[s] * dis[d];
    }
}

// ghost prep + compaction: ghost_pos[node] = slot or -1; ghost_list[slot] = node
__global__ void ghost_kernel(const int* __restrict__ mask, const int* __restrict__ first_out,
                             const float* __restrict__ first_dx,
                             int* d1_of, int* d2_of, float* dxb_of,
                             int* ghost_list, int* ghost_pos, int* gcount, int n) {
    int i = blockIdx.x * 256 + threadIdx.x;
    if (i >= n) return;
    if (mask[i] != 0) { ghost_pos[i] = -1; return; }
    int pos = atomicAdd(gcount, 1);
    ghost_list[pos] = i;
    ghost_pos[i] = pos;
    int b = first_out[i];
    float dxb = fmaxf(first_dx[i], 1e-6f);
    int d1, d2;
    if (b < 0) { d1 = i; d2 = i; }
    else {
        int n1 = first_out[b]; d1 = (n1 < 0) ? b : n1;
        int n2 = first_out[d1]; d2 = (n2 < 0) ? d1 : n2;
    }
    d1_of[i] = d1; d2_of[i] = d2; dxb_of[i] = dxb;
}

// zero two regions in one dispatch (grid-stride)
__global__ void zero2_kernel(float* a, int na, unsigned* b, int nb) {
    int stride = gridDim.x * 256;
    for (int i = blockIdx.x * 256 + threadIdx.x; i < na; i += stride) a[i] = 0.0f;
    for (int i = blockIdx.x * 256 + threadIdx.x; i < nb; i += stride) b[i] = 0u;
}

// W[k][nn] (K=128) -> BT_hi/BT_lo[nn][k] bf16 split, LDS-tiled transpose (coalesced both sides)
__global__ __launch_bounds__(256)
void wsplit_kernel(const float* __restrict__ W, u16* BT_hi, u16* BT_lo, int Ncols) {
    __shared__ float tile[32][33];
    int nb = blockIdx.x * 32;           // column-of-W (=row-of-BT) base
    int kb = blockIdx.y * 32;           // k base
    int tx = threadIdx.x & 31, ty = threadIdx.x >> 5;   // 32 x 8
    #pragma unroll
    for (int r = 0; r < 32; r += 8)
        tile[ty + r][tx] = W[(size_t)(kb + ty + r) * Ncols + nb + tx];
    __syncthreads();
    #pragma unroll
    for (int r = 0; r < 32; r += 8) {
        float v = tile[tx][ty + r];     // = W[kb+tx][nb+ty+r]
        u16 h = f2b(v);
        size_t off = (size_t)(nb + ty + r) * 128 + kb + tx;
        BT_hi[off] = h;
        BT_lo[off] = f2b(v - b2f(h));
    }
}

// ---------------- batched front-end kernels ----------------

// Ghost fusion only: blockIdx.x = ghost slot (exit if >= gcount), blockIdx.y = t.
// Writes fused 16-vector to xf_buf[slot][t][16].
__global__ __launch_bounds__(128)
void fuse_ghost(const float* __restrict__ x,
                const int* __restrict__ ghost_list, const int* __restrict__ gcount,
                const int* __restrict__ d1_of, const int* __restrict__ d2_of,
                const float* __restrict__ dxb_of,
                const float* __restrict__ Wf1, const float* __restrict__ bf1,
                const float* __restrict__ Wf2, const float* __restrict__ bf2,
                const float* __restrict__ Wg1, const float* __restrict__ bg1,
                const float* __restrict__ Wg2, const float* __restrict__ bg2,
                float* __restrict__ xf_buf) {
    int slot = blockIdx.x;
    if (slot >= *gcount) return;
    int t = blockIdx.y;
    int i = ghost_list[slot];
    int j = threadIdx.x;
    __shared__ float feats[FUSER_IN];
    __shared__ float z1[FUSER_H];
    __shared__ float zg[GATE_H];
    __shared__ float s_gate;

    if (j < FEAT) {
        int d1 = d1_of[i], d2 = d2_of[i];
        feats[j]            = x[((size_t)i * T_IN + t) * FEAT + j];
        feats[FEAT + j]     = x[((size_t)d1 * T_IN + t) * FEAT + j];
        feats[2 * FEAT + j] = x[((size_t)d2 * T_IN + t) * FEAT + j];
    }
    if (j == 0) feats[3 * FEAT] = dxb_of[i];
    __syncthreads();
    if (j < FUSER_H) {
        float acc = bf1[j];
        for (int k = 0; k < FUSER_IN; ++k) acc = fmaf(feats[k], Wf1[k * FUSER_H + j], acc);
        z1[j] = fmaxf(acc, 0.0f);
    }
    if (j < GATE_H) {
        float acc = bg1[j];
        for (int k = 0; k < FUSER_IN; ++k) acc = fmaf(feats[k], Wg1[k * GATE_H + j], acc);
        zg[j] = fmaxf(acc, 0.0f);
    }
    __syncthreads();
    if (j == 0) {
        float s = bg2[0];
        for (int k = 0; k < GATE_H; ++k) s = fmaf(zg[k], Wg2[k], s);
        s_gate = sigmoidf_(s);
    }
    __syncthreads();
    if (j < FEAT) {
        float acc = bf2[j];
        for (int k = 0; k < FUSER_H; ++k) acc = fmaf(z1[k], Wf2[k * FEAT + j], acc);
        xf_buf[((size_t)slot * T_IN + t) * FEAT + j] = feats[j] + ALPHA * acc * s_gate;
    }
}

// g = relu(xf @ W_lin + b_lin) for ALL (t,node) pairs. Grid-stride, 2 pairs/block,
// W_lin+b_lin cached in LDS. Output g8[t][node][128] bf16 hi/lo.
__global__ __launch_bounds__(256)
void lin_all(const float* __restrict__ x, const float* __restrict__ xf_buf,
             const int* __restrict__ ghost_pos,
             const float* __restrict__ W_lin, const float* __restrict__ b_lin,
             u16* __restrict__ g8_hi, u16* __restrict__ g8_lo, int n, int total) {
    __shared__ float Wl[FEAT][HID];
    __shared__ float bl[HID];
    #pragma unroll
    for (int k8 = 0; k8 < 8; ++k8) {
        int idx = threadIdx.x + k8 * 256;
        Wl[idx >> 7][idx & 127] = W_lin[idx];
    }
    if (threadIdx.x < HID) bl[threadIdx.x] = b_lin[threadIdx.x];
    __syncthreads();
    int j = threadIdx.x & 127;
    for (int pair = blockIdx.x * 2 + (threadIdx.x >> 7); pair < total; pair += gridDim.x * 2) {
        int node = pair % n;
        int t = pair / n;
        int gp = ghost_pos[node];
        const float* xr = (gp >= 0) ? &xf_buf[((size_t)gp * T_IN + t) * FEAT]
                                    : &x[((size_t)node * T_IN + t) * FEAT];
        float acc = bl[j];
        #pragma unroll
        for (int k = 0; k < FEAT; ++k) acc = fmaf(xr[k], Wl[k][j], acc);
        float v = fmaxf(acc, 0.0f);
        u16 hv = f2b(v);
        size_t off = (size_t)pair * HID + j;
        g8_hi[off] = hv;
        g8_lo[off] = f2b(v - b2f(hv));
    }
}

// Batched GCN GEMM: Cb[t][M x 128] = bf16(A[t] @ B), bf16x3 MFMA. BM=64, blockIdx.z = t.
__global__ __launch_bounds__(256)
void gemm_gcn_b(const u16* __restrict__ Ahi0, const u16* __restrict__ Alo0,
                const u16* __restrict__ BThi, const u16* __restrict__ BTlo,
                u16* __restrict__ Cb0, int M) {
    constexpr int BM = 64;
    __shared__ u16 ldsA[2][BM * 128];
    const size_t tOff = (size_t)blockIdx.z * M * 128;
    const u16* Ahi = Ahi0 + tOff;
    const u16* Alo = Alo0 + tOff;
    u16*       Cb  = Cb0 + tOff;

    const int tid  = threadIdx.x;
    const int row0 = blockIdx.x * BM;
    constexpr int MF = BM / 32;

    #pragma unroll
    for (int it = 0; it < BM / 16; ++it) {
        int unit = tid + it * 256;
        int r = unit >> 4, s = unit & 15;
        int gr = row0 + r;
        uint4 vh = make_uint4(0, 0, 0, 0), vl = vh;
        if (gr < M) {
            vh = *reinterpret_cast<const uint4*>(&Ahi[(size_t)gr * 128 + s * 8]);
            vl = *reinterpret_cast<const uint4*>(&Alo[(size_t)gr * 128 + s * 8]);
        }
        int byte = (r * 256 + s * 16) ^ ((r & 7) << 4);
        *reinterpret_cast<uint4*>((char*)(&ldsA[0][0]) + byte) = vh;
        *reinterpret_cast<uint4*>((char*)(&ldsA[1][0]) + byte) = vl;
    }
    __syncthreads();

    const int wid  = tid >> 6;
    const int lane = tid & 63;
    const int wr = (wid >> 1) * (BM / 2);
    const int wc = (wid & 1) * 64;
    const int l15 = lane & 15;
    const int lkh = lane >> 4;

    f32x4_t acc[MF][4] = {};

    #pragma unroll
    for (int kb = 0; kb < 4; ++kb) {
        bf16x8_t ah[MF], al[MF], bh[4], bl[4];
        #pragma unroll
        for (int m = 0; m < MF; ++m) {
            int row = wr + m * 16 + l15;
            int byte = (row * 256 + kb * 64 + lkh * 16) ^ ((row & 7) << 4);
            ah[m] = *reinterpret_cast<const bf16x8_t*>((const char*)(&ldsA[0][0]) + byte);
            al[m] = *reinterpret_cast<const bf16x8_t*>((const char*)(&ldsA[1][0]) + byte);
        }
        #pragma unroll
        for (int nf = 0; nf < 4; ++nf) {
            int col = wc + nf * 16 + l15;
            size_t off = (size_t)col * 128 + kb * 32 + lkh * 8;
            bh[nf] = *reinterpret_cast<const bf16x8_t*>(&BThi[off]);
            bl[nf] = *reinterpret_cast<const bf16x8_t*>(&BTlo[off]);
        }
        #pragma unroll
        for (int m = 0; m < MF; ++m)
            #pragma unroll
            for (int nf = 0; nf < 4; ++nf) {
                acc[m][nf] = __builtin_amdgcn_mfma_f32_16x16x32_bf16(ah[m], bh[nf], acc[m][nf], 0, 0, 0);
                acc[m][nf] = __builtin_amdgcn_mfma_f32_16x16x32_bf16(ah[m], bl[nf], acc[m][nf], 0, 0, 0);
                acc[m][nf] = __builtin_amdgcn_mfma_f32_16x16x32_bf16(al[m], bh[nf], acc[m][nf], 0, 0, 0);
            }
    }

    #pragma unroll
    for (int m = 0; m < MF; ++m) {
        int rbase = row0 + wr + m * 16 + lkh * 4;
        #pragma unroll
        for (int nf = 0; nf < 4; ++nf) {
            int col = wc + nf * 16 + l15;
            #pragma unroll
            for (int r2 = 0; r2 < 4; ++r2) {
                int row = rbase + r2;
                if (row < M) Cb[(size_t)row * 128 + col] = f2b(acc[m][nf][r2]);
            }
        }
    }
}

// Batched GCN aggregate, all-bf16 inputs. 1D grid with t = blockIdx.x & 7 so each
// XCD's L2 (round-robin dispatch) holds one t-slab of hwb. 32 threads/node.
__global__ __launch_bounds__(256)
void gcn_agg_b(const u16* __restrict__ hwb0,
               const int* __restrict__ row_ptr,
               const int* __restrict__ csr_src, const float* __restrict__ csr_w,
               const float* __restrict__ norm_self, const float* __restrict__ bias,
               u16* __restrict__ g_hi0, u16* __restrict__ g_lo0, int n) {
    int t   = blockIdx.x & 7;
    int blk = blockIdx.x >> 3;
    int node = blk * 8 + (threadIdx.x >> 5);
    int lane = threadIdx.x & 31;
    if (node >= n) return;
    const size_t tOff = (size_t)t * n * 128;
    const u16* hwb = hwb0 + tOff;
    u16* g_hi = g_hi0 + tOff;
    u16* g_lo = g_lo0 + tOff;

    ushort4 sv = *reinterpret_cast<const ushort4*>(&hwb[(size_t)node * HID + lane * 4]);
    float ns = norm_self[node];
    float4 a0, a1, a2, a3;
    a0.x = b2f(sv.x) * ns; a0.y = b2f(sv.y) * ns; a0.z = b2f(sv.z) * ns; a0.w = b2f(sv.w) * ns;
    a1 = make_float4(0.f, 0.f, 0.f, 0.f); a2 = a1; a3 = a1;
    int p  = row_ptr[node];
    int p1 = row_ptr[node + 1];
    for (; p + 4 <= p1; p += 4) {
        int s0 = csr_src[p], s1 = csr_src[p + 1], s2 = csr_src[p + 2], s3 = csr_src[p + 3];
        float w0 = csr_w[p], w1 = csr_w[p + 1], w2 = csr_w[p + 2], w3 = csr_w[p + 3];
        ushort4 v0 = *reinterpret_cast<const ushort4*>(&hwb[(size_t)s0 * HID + lane * 4]);
        ushort4 v1 = *reinterpret_cast<const ushort4*>(&hwb[(size_t)s1 * HID + lane * 4]);
        ushort4 v2 = *reinterpret_cast<const ushort4*>(&hwb[(size_t)s2 * HID + lane * 4]);
        ushort4 v3 = *reinterpret_cast<const ushort4*>(&hwb[(size_t)s3 * HID + lane * 4]);
        a0.x = fmaf(b2f(v0.x), w0, a0.x); a0.y = fmaf(b2f(v0.y), w0, a0.y);
        a0.z = fmaf(b2f(v0.z), w0, a0.z); a0.w = fmaf(b2f(v0.w), w0, a0.w);
        a1.x = fmaf(b2f(v1.x), w1, a1.x); a1.y = fmaf(b2f(v1.y), w1, a1.y);
        a1.z = fmaf(b2f(v1.z), w1, a1.z); a1.w = fmaf(b2f(v1.w), w1, a1.w);
        a2.x = fmaf(b2f(v2.x), w2, a2.x); a2.y = fmaf(b2f(v2.y), w2, a2.y);
        a2.z = fmaf(b2f(v2.z), w2, a2.z); a2.w = fmaf(b2f(v2.w), w2, a2.w);
        a3.x = fmaf(b2f(v3.x), w3, a3.x); a3.y = fmaf(b2f(v3.y), w3, a3.y);
        a3.z = fmaf(b2f(v3.z), w3, a3.z); a3.w = fmaf(b2f(v3.w), w3, a3.w);
    }
    for (; p < p1; ++p) {
        int s = csr_src[p];
        float w = csr_w[p];
        ushort4 v = *reinterpret_cast<const ushort4*>(&hwb[(size_t)s * HID + lane * 4]);
        a0.x = fmaf(b2f(v.x), w, a0.x); a0.y = fmaf(b2f(v.y), w, a0.y);
        a0.z = fmaf(b2f(v.z), w, a0.z); a0.w = fmaf(b2f(v.w), w, a0.w);
    }
    float4 b4 = reinterpret_cast<const float4*>(bias)[lane];
    float ox = fmaxf(a0.x + a1.x + a2.x + a3.x + b4.x, 0.0f);
    float oy = fmaxf(a0.y + a1.y + a2.y + a3.y + b4.y, 0.0f);
    float oz = fmaxf(a0.z + a1.z + a2.z + a3.z + b4.z, 0.0f);
    float ow = fmaxf(a0.w + a1.w + a2.w + a3.w + b4.w, 0.0f);
    ushort4 hv, lv;
    hv.x = f2b(ox); lv.x = f2b(ox - b2f(hv.x));
    hv.y = f2b(oy); lv.y = f2b(oy - b2f(hv.y));
    hv.z = f2b(oz); lv.z = f2b(oz - b2f(hv.z));
    hv.w = f2b(ow); lv.w = f2b(ow - b2f(hv.w));
    *reinterpret_cast<ushort4*>(&g_hi[(size_t)node * HID + lane * 4]) = hv;
    *reinterpret_cast<ushort4*>(&g_lo[(size_t)node * HID + lane * 4]) = lv;
}

// ---------------- sequential GRU kernels ----------------

// Dual GEMM: blockIdx.z=0 -> C1 = A1@B1 (gi), z=1 -> C2 = A2@B2 (gh). BM=128, BN=128.
__global__ __launch_bounds__(256)
void gemm_gru(const u16* __restrict__ Ahi1, const u16* __restrict__ Alo1,
              const u16* __restrict__ BThi1, const u16* __restrict__ BTlo1,
              float* __restrict__ C1,
              const u16* __restrict__ Ahi2, const u16* __restrict__ Alo2,
              const u16* __restrict__ BThi2, const u16* __restrict__ BTlo2,
              float* __restrict__ C2,
              int M, int Ncols) {
    constexpr int BM = 128;
    __shared__ u16 ldsA[2][BM * 128];
    const u16* Ahi  = blockIdx.z ? Ahi2  : Ahi1;
    const u16* Alo  = blockIdx.z ? Alo2  : Alo1;
    const u16* BThi = blockIdx.z ? BThi2 : BThi1;
    const u16* BTlo = blockIdx.z ? BTlo2 : BTlo1;
    float*     C    = blockIdx.z ? C2    : C1;

    const int tid  = threadIdx.x;
    const int row0 = blockIdx.x * BM;
    const int col0 = blockIdx.y * 128;
    constexpr int MF = BM / 32;

    #pragma unroll
    for (int it = 0; it < BM / 16; ++it) {
        int unit = tid + it * 256;
        int r = unit >> 4, s = unit & 15;
        int gr = row0 + r;
        uint4 vh = make_uint4(0, 0, 0, 0), vl = vh;
        if (gr < M) {
            vh = *reinterpret_cast<const uint4*>(&Ahi[(size_t)gr * 128 + s * 8]);
            vl = *reinterpret_cast<const uint4*>(&Alo[(size_t)gr * 128 + s * 8]);
        }
        int byte = (r * 256 + s * 16) ^ ((r & 7) << 4);
        *reinterpret_cast<uint4*>((char*)(&ldsA[0][0]) + byte) = vh;
        *reinterpret_cast<uint4*>((char*)(&ldsA[1][0]) + byte) = vl;
    }
    __syncthreads();

    const int wid  = tid >> 6;
    const int lane = tid & 63;
    const int wr = (wid >> 1) * (BM / 2);
    const int wc = (wid & 1) * 64;
    const int l15 = lane & 15;
    const int lkh = lane >> 4;

    f32x4_t acc[MF][4] = {};

    #pragma unroll
    for (int kb = 0; kb < 4; ++kb) {
        bf16x8_t ah[MF], al[MF], bh[4], bl[4];
        #pragma unroll
        for (int m = 0; m < MF; ++m) {
            int row = wr + m * 16 + l15;
            int byte = (row * 256 + kb * 64 + lkh * 16) ^ ((row & 7) << 4);
            ah[m] = *reinterpret_cast<const bf16x8_t*>((const char*)(&ldsA[0][0]) + byte);
            al[m] = *reinterpret_cast<const bf16x8_t*>((const char*)(&ldsA[1][0]) + byte);
        }
        #pragma unroll
        for (int nf = 0; nf < 4; ++nf) {
            int col = col0 + wc + nf * 16 + l15;
            size_t off = (size_t)col * 128 + kb * 32 + lkh * 8;
            bh[nf] = *reinterpret_cast<const bf16x8_t*>(&BThi[off]);
            bl[nf] = *reinterpret_cast<const bf16x8_t*>(&BTlo[off]);
        }
        #pragma unroll
        for (int m = 0; m < MF; ++m)
            #pragma unroll
            for (int nf = 0; nf < 4; ++nf) {
                acc[m][nf] = __builtin_amdgcn_mfma_f32_16x16x32_bf16(ah[m], bh[nf], acc[m][nf], 0, 0, 0);
                acc[m][nf] = __builtin_amdgcn_mfma_f32_16x16x32_bf16(ah[m], bl[nf], acc[m][nf], 0, 0, 0);
                acc[m][nf] = __builtin_amdgcn_mfma_f32_16x16x32_bf16(al[m], bh[nf], acc[m][nf], 0, 0, 0);
            }
    }

    #pragma unroll
    for (int m = 0; m < MF; ++m) {
        int rbase = row0 + wr + m * 16 + lkh * 4;
        #pragma unroll
        for (int nf = 0; nf < 4; ++nf) {
            int col = col0 + wc + nf * 16 + l15;
            #pragma unroll
            for (int r2 = 0; r2 < 4; ++r2) {
                int row = rbase + r2;
                if (row < M) C[(size_t)row * Ncols + col] = acc[m][nf][r2];
            }
        }
    }
}

__global__ __launch_bounds__(256)
void gru_kernel(const float* __restrict__ gi, const float* __restrict__ gh,
                const float* __restrict__ b_ih, const float* __restrict__ b_hh,
                float* __restrict__ h, u16* __restrict__ h_hi, u16* __restrict__ h_lo, int n) {
    int idx = blockIdx.x * 256 + threadIdx.x;     // one float4 of h per thread
    if (idx >= n * 32) return;
    int row = idx >> 5, q = idx & 31;
    const float4* gi4 = reinterpret_cast<const float4*>(gi + (size_t)row * H3);
    const float4* gh4 = reinterpret_cast<const float4*>(gh + (size_t)row * H3);
    const float4* bi4 = reinterpret_cast<const float4*>(b_ih);
    const float4* bh4 = reinterpret_cast<const float4*>(b_hh);
    float4 vir = gi4[q], viz = gi4[32 + q], vin = gi4[64 + q];
    float4 vhr = gh4[q], vhz = gh4[32 + q], vhn = gh4[64 + q];
    float4 bir = bi4[q], biz = bi4[32 + q], bin_ = bi4[64 + q];
    float4 bhr = bh4[q], bhz = bh4[32 + q], bhn = bh4[64 + q];
    float4* h4 = reinterpret_cast<float4*>(h);
    float4 hv = h4[idx];
    float4 o;
    {
        float r = sigmoidf_((vir.x + bir.x) + (vhr.x + bhr.x));
        float z = sigmoidf_((viz.x + biz.x) + (vhz.x + bhz.x));
        float nn2 = tanhf((vin.x + bin_.x) + r * (vhn.x + bhn.x));
        o.x = (1.0f - z) * nn2 + z * hv.x;
    }
    {
        float r = sigmoidf_((vir.y + bir.y) + (vhr.y + bhr.y));
        float z = sigmoidf_((viz.y + biz.y) + (vhz.y + bhz.y));
        float nn2 = tanhf((vin.y + bin_.y) + r * (vhn.y + bhn.y));
        o.y = (1.0f - z) * nn2 + z * hv.y;
    }
    {
        float r = sigmoidf_((vir.z + bir.z) + (vhr.z + bhr.z));
        float z = sigmoidf_((viz.z + biz.z) + (vhz.z + bhz.z));
        float nn2 = tanhf((vin.z + bin_.z) + r * (vhn.z + bhn.z));
        o.z = (1.0f - z) * nn2 + z * hv.z;
    }
    {
        float r = sigmoidf_((vir.w + bir.w) + (vhr.w + bhr.w));
        float z = sigmoidf_((viz.w + biz.w) + (vhz.w + bhz.w));
        float nn2 = tanhf((vin.w + bin_.w) + r * (vhn.w + bhn.w));
        o.w = (1.0f - z) * nn2 + z * hv.w;
    }
    h4[idx] = o;
    ushort4 hvv, lvv;
    hvv.x = f2b(o.x); lvv.x = f2b(o.x - b2f(hvv.x));
    hvv.y = f2b(o.y); lvv.y = f2b(o.y - b2f(hvv.y));
    hvv.z = f2b(o.z); lvv.z = f2b(o.z - b2f(hvv.z));
    hvv.w = f2b(o.w); lvv.w = f2b(o.w - b2f(hvv.w));
    *reinterpret_cast<ushort4*>(&h_hi[(size_t)row * HID + q * 4]) = hvv;
    *reinterpret_cast<ushort4*>(&h_lo[(size_t)row * HID + q * 4]) = lvv;
}

// ---------------- launcher ----------------

extern "C" void kernel_launch(void* const* d_in, const int* in_sizes, int n_in,
                              void* d_out, int out_size, void* d_ws, size_t ws_size,
                              hipStream_t stream) {
    const float* x        = (const float*)d_in[0];
    const float* edge_attr= (const float*)d_in[1];
    const float* W_lin    = (const float*)d_in[2];
    const float* b_lin    = (const float*)d_in[3];
    const float* Wc1      = (const float*)d_in[4];
    const float* bc1      = (const float*)d_in[5];
    const float* Wc2      = (const float*)d_in[6];
    const float* bc2      = (const float*)d_in[7];
    const float* W_ih     = (const float*)d_in[8];
    const float* b_ih     = (const float*)d_in[9];
    const float* W_hh     = (const float*)d_in[10];
    const float* b_hh     = (const float*)d_in[11];
    const float* Wf1      = (const float*)d_in[12];
    const float* bf1      = (const float*)d_in[13];
    const float* Wf2      = (const float*)d_in[14];
    const float* bf2      = (const float*)d_in[15];
    const float* Wg1      = (const float*)d_in[16];
    const float* bg1      = (const float*)d_in[17];
    const float* Wg2      = (const float*)d_in[18];
    const float* bg2      = (const float*)d_in[19];
    const int*   edge_index = (const int*)d_in[20];
    const int*   mask     = (const int*)d_in[21];

    const int n = in_sizes[21];       // 20000
    const int e = in_sizes[1];        // 320000
    const int* src = edge_index;
    const int* dst = edge_index + e;
    float* h = (float*)d_out;         // [n,128], GRU state (fp32)

    char* w = (char*)d_ws;
    auto alloc = [&](size_t bytes) -> char* {
        char* p = w;
        w += (bytes + 255) & ~(size_t)255;
        return p;
    };
    int*   first_eid = (int*)  alloc((size_t)n * 4);
    int*   deg_cnt   = (int*)  alloc((size_t)n * 4);
    int*   row_ptr   = (int*)  alloc((size_t)(n + 1) * 4);
    int*   fill_ptr  = (int*)  alloc((size_t)n * 4);
    int*   tmp_scan  = (int*)  alloc((size_t)n * 4);
    int*   bsum      = (int*)  alloc((size_t)256 * 4);
    float* dis       = (float*)alloc((size_t)n * 4);
    float* norm_self = (float*)alloc((size_t)n * 4);
    int*   first_out = (int*)  alloc((size_t)n * 4);
    float* first_dx  = (float*)alloc((size_t)n * 4);
    int*   d1_of     = (int*)  alloc((size_t)n * 4);
    int*   d2_of     = (int*)  alloc((size_t)n * 4);
    float* dxb_of    = (float*)alloc((size_t)n * 4);
    int*   ghost_list= (int*)  alloc((size_t)n * 4);
    int*   ghost_pos = (int*)  alloc((size_t)n * 4);
    int*   gcount    = (int*)  alloc(256);
    int*   csr_src   = (int*)  alloc((size_t)e * 4);
    float* csr_w     = (float*)alloc((size_t)e * 4);
    // bf16 split weight transposes BT[n][k]
    u16* Wc1T_hi = (u16*)alloc((size_t)HID * 128 * 2);
    u16* Wc1T_lo = (u16*)alloc((size_t)HID * 128 * 2);
    u16* Wc2T_hi = (u16*)alloc((size_t)HID * 128 * 2);
    u16* Wc2T_lo = (u16*)alloc((size_t)HID * 128 * 2);
    u16* WihT_hi = (u16*)alloc((size_t)H3 * 128 * 2);
    u16* WihT_lo = (u16*)alloc((size_t)H3 * 128 * 2);
    u16* WhhT_hi = (u16*)alloc((size_t)H3 * 128 * 2);
    u16* WhhT_lo = (u16*)alloc((size_t)H3 * 128 * 2);
    // activations (batched over all T_IN)
    u16*   g8_hi = (u16*)  alloc((size_t)T_IN * n * HID * 2);   // 41 MB
    u16*   g8_lo = (u16*)  alloc((size_t)T_IN * n * HID * 2);   // 41 MB
    u16*   bufHb = (u16*)  alloc((size_t)T_IN * n * HID * 2);   // 41 MB
    float* bufGi = (float*)alloc((size_t)n * H3 * 4);           // 31 MB
    float* bufGh = (float*)alloc((size_t)n * H3 * 4);           // 31 MB
    float* xf_buf= (float*)alloc((size_t)n * T_IN * FEAT * 4);  // 41 MB (ghost-capacity safe)
    u16*   h_hi  = (u16*)  alloc((size_t)n * HID * 2);          // adjacent to h_lo
    u16*   h_lo  = (u16*)  alloc((size_t)n * HID * 2);

    const int TPB = 256;
    const int nb = (n + 255) / 256;
    dim3 gN(nb), gE((e + TPB - 1) / TPB);

    // preprocessing (time-invariant)
    init_kernel<<<gN, TPB, 0, stream>>>(first_eid, deg_cnt, gcount, n);
    edge_pass1<<<gE, TPB, 0, stream>>>(src, dst, first_eid, deg_cnt, e);
    scan1<<<gN, TPB, 0, stream>>>(deg_cnt, tmp_scan, bsum, n);
    scan2<<<1, TPB, 0, stream>>>(bsum, nb);
    scan3<<<gN, TPB, 0, stream>>>(deg_cnt, tmp_scan, bsum, row_ptr, fill_ptr, dis, norm_self, n);
    firsts_kernel<<<gN, TPB, 0, stream>>>(first_eid, dst, edge_attr, first_out, first_dx, n, e);
    edge_pass2<<<gE, TPB, 0, stream>>>(src, dst, fill_ptr, dis, csr_src, csr_w, e);
    ghost_kernel<<<gN, TPB, 0, stream>>>(mask, first_out, first_dx, d1_of, d2_of, dxb_of,
                                         ghost_list, ghost_pos, gcount, n);
    wsplit_kernel<<<dim3(HID / 32, 4), TPB, 0, stream>>>(Wc1, Wc1T_hi, Wc1T_lo, HID);
    wsplit_kernel<<<dim3(HID / 32, 4), TPB, 0, stream>>>(Wc2, Wc2T_hi, Wc2T_lo, HID);
    wsplit_kernel<<<dim3(H3 / 32, 4), TPB, 0, stream>>>(W_ih, WihT_hi, WihT_lo, H3);
    wsplit_kernel<<<dim3(H3 / 32, 4), TPB, 0, stream>>>(W_hh, WhhT_hi, WhhT_lo, H3);

    // h0 = 0 (fp32) and split hi/lo (adjacent region, as u32 words)
    zero2_kernel<<<2048, TPB, 0, stream>>>(h, n * HID, (unsigned*)h_hi, n * HID);

    // ---- Phase A: front end for ALL timesteps (independent of h) ----
    fuse_ghost<<<dim3(n, T_IN), 128, 0, stream>>>(x, ghost_list, gcount, d1_of, d2_of, dxb_of,
                                                  Wf1, bf1, Wf2, bf2, Wg1, bg1, Wg2, bg2,
                                                  xf_buf);
    lin_all<<<2048, 256, 0, stream>>>(x, xf_buf, ghost_pos, W_lin, b_lin,
                                      g8_hi, g8_lo, n, n * T_IN);
    dim3 grid_gcn((n + 63) / 64, 1, T_IN);
    const int agg_blocks = ((n + 7) / 8) * T_IN;
    gemm_gcn_b<<<grid_gcn, 256, 0, stream>>>(g8_hi, g8_lo, Wc1T_hi, Wc1T_lo, bufHb, n);
    gcn_agg_b<<<agg_blocks, 256, 0, stream>>>(bufHb, row_ptr, csr_src, csr_w,
                                              norm_self, bc1, g8_hi, g8_lo, n);
    gemm_gcn_b<<<grid_gcn, 256, 0, stream>>>(g8_hi, g8_lo, Wc2T_hi, Wc2T_lo, bufHb, n);
    gcn_agg_b<<<agg_blocks, 256, 0, stream>>>(bufHb, row_ptr, csr_src, csr_w,
                                              norm_self, bc2, g8_hi, g8_lo, n);

    // ---- Phase B: sequential GRU over timesteps ----
    dim3 grid_gru((n + 127) / 128, 3, 2);
    for (int t = 0; t < T_IN; ++t) {
        const u16* Gt_hi = g8_hi + (size_t)t * n * HID;
        const u16* Gt_lo = g8_lo + (size_t)t * n * HID;
        gemm_gru<<<grid_gru, 256, 0, stream>>>(
            Gt_hi, Gt_lo, WihT_hi, WihT_lo, bufGi,
            h_hi, h_lo, WhhT_hi, WhhT_lo, bufGh, n, H3);
        gru_kernel<<<(n * 32 + TPB - 1) / TPB, TPB, 0, stream>>>(bufGi, bufGh, b_ih, b_hh,
                                                                 h, h_hi, h_lo, n);
    }
}